// Round 1
// baseline (14395.457 us; speedup 1.0000x reference)
//
#include <hip/hip_runtime.h>
#include <math.h>

#define B_ 2
#define T_ 2048
#define C_ 1024
#define H_ 16
#define D_ 64
#define CS_ 64
#define NC_ 32
#define NS_ 5

// ---------------------------------------------------------------------------
// GEMM: out[M][N] = A[M][K] * Bw[N][K]^T   (row-major, both operands row-dot-row)
// 64x64 tile per 256-thread block, 4x4 register tile per thread, BK=32.
// ---------------------------------------------------------------------------
template<int M, int N, int K>
__global__ __launch_bounds__(256) void gemm_abt(const float* __restrict__ A,
                                                const float* __restrict__ Bw,
                                                float* __restrict__ out) {
    __shared__ float As[64][36];
    __shared__ float Bs[64][36];
    int tid = threadIdx.x;
    int m0 = blockIdx.y * 64, n0 = blockIdx.x * 64;
    int r0 = (tid >> 4) * 4, c0 = (tid & 15) * 4;
    float acc[4][4] = {};
    for (int kt = 0; kt < K; kt += 32) {
        int lr = tid >> 3, lc = (tid & 7) * 4;
        *(float4*)&As[lr][lc]      = *(const float4*)&A[(m0 + lr) * K + kt + lc];
        *(float4*)&As[lr + 32][lc] = *(const float4*)&A[(m0 + lr + 32) * K + kt + lc];
        *(float4*)&Bs[lr][lc]      = *(const float4*)&Bw[(n0 + lr) * K + kt + lc];
        *(float4*)&Bs[lr + 32][lc] = *(const float4*)&Bw[(n0 + lr + 32) * K + kt + lc];
        __syncthreads();
        #pragma unroll
        for (int kk = 0; kk < 32; kk += 4) {
            float4 a4[4], b4[4];
            #pragma unroll
            for (int i = 0; i < 4; i++) a4[i] = *(float4*)&As[r0 + i][kk];
            #pragma unroll
            for (int j = 0; j < 4; j++) b4[j] = *(float4*)&Bs[c0 + j][kk];
            #pragma unroll
            for (int i = 0; i < 4; i++)
                #pragma unroll
                for (int j = 0; j < 4; j++)
                    acc[i][j] += a4[i].x * b4[j].x + a4[i].y * b4[j].y
                               + a4[i].z * b4[j].z + a4[i].w * b4[j].w;
        }
        __syncthreads();
    }
    #pragma unroll
    for (int i = 0; i < 4; i++) {
        float4 o = make_float4(acc[i][0], acc[i][1], acc[i][2], acc[i][3]);
        *(float4*)&out[(m0 + r0 + i) * N + n0 + c0] = o;
    }
}

// ---------------------------------------------------------------------------
// Causal depthwise conv (K=4) + optional per-head RMS norm + optional poly.
// mode: 0 = conv only (v), 1 = conv+rms (q), 2 = conv+rms+poly (k)
// One block per (b,t); thread handles 4 channels.
// ---------------------------------------------------------------------------
__global__ __launch_bounds__(256) void conv_kernel(const float* __restrict__ xin,
                                                   const float* __restrict__ w,
                                                   const float* __restrict__ bias,
                                                   float* __restrict__ out, int mode) {
    int bt = blockIdx.x;               // b*T + t
    int t = bt & (T_ - 1);
    int tid = threadIdx.x;
    int c0 = tid * 4;
    float4 w4[4];
    #pragma unroll
    for (int i = 0; i < 4; i++) w4[i] = *(const float4*)&w[(c0 + i) * 4];
    float4 bi = *(const float4*)&bias[c0];
    float4 xs[4];
    #pragma unroll
    for (int j = 0; j < 4; j++) {
        int tt = t - 3 + j;
        xs[j] = (tt >= 0) ? *(const float4*)&xin[(bt - 3 + j) * C_ + c0]
                          : make_float4(0.f, 0.f, 0.f, 0.f);
    }
    float y0 = bi.x + w4[0].x * xs[0].x + w4[0].y * xs[1].x + w4[0].z * xs[2].x + w4[0].w * xs[3].x;
    float y1 = bi.y + w4[1].x * xs[0].y + w4[1].y * xs[1].y + w4[1].z * xs[2].y + w4[1].w * xs[3].y;
    float y2 = bi.z + w4[2].x * xs[0].z + w4[2].y * xs[1].z + w4[2].z * xs[2].z + w4[2].w * xs[3].z;
    float y3 = bi.w + w4[3].x * xs[0].w + w4[3].y * xs[1].w + w4[3].z * xs[2].w + w4[3].w * xs[3].w;
    if (mode >= 1) {
        float ss = y0 * y0 + y1 * y1 + y2 * y2 + y3 * y3;
        ss += __shfl_xor(ss, 1);
        ss += __shfl_xor(ss, 2);
        ss += __shfl_xor(ss, 4);
        ss += __shfl_xor(ss, 8);
        float sc = rsqrtf(ss * (1.f / 64.f) + 1e-6f);
        y0 *= sc; y1 *= sc; y2 *= sc; y3 *= sc;
        if (mode == 2) {   // phi(k) = k + 0.5 k^2
            y0 += 0.5f * y0 * y0; y1 += 0.5f * y1 * y1;
            y2 += 0.5f * y2 * y2; y3 += 0.5f * y3 * y3;
        }
    }
    *(float4*)&out[bt * C_ + c0] = make_float4(y0, y1, y2, y3);
}

// ---------------------------------------------------------------------------
// Gate projections: gates[g][b*T+t][h] = sigmoid(x[b,t,:] . W_g[h,:])
// g: 0=alpha(Wa) 1=eta(We) 2=theta(Wt) 3=gamma(Wg). One block per (b,t).
// ---------------------------------------------------------------------------
__global__ __launch_bounds__(256) void gates_kernel(const float* __restrict__ x,
                                                    const float* __restrict__ Wa,
                                                    const float* __restrict__ We,
                                                    const float* __restrict__ Wt,
                                                    const float* __restrict__ Wg,
                                                    float* __restrict__ gates) {
    __shared__ float xs[C_];
    int bt = blockIdx.x, tid = threadIdx.x;
    *(float4*)&xs[tid * 4] = *(const float4*)&x[bt * C_ + tid * 4];
    __syncthreads();
    int dot = tid >> 2, l = tid & 3;
    int g = dot >> 4, h = dot & 15;
    const float* Wp = (g == 0) ? Wa : (g == 1) ? We : (g == 2) ? Wt : Wg;
    const float* Wr = Wp + h * C_;
    float p = 0.f;
    for (int c = l * 4; c < C_; c += 16) {
        float4 wv = *(const float4*)&Wr[c];
        float4 xv = *(const float4*)&xs[c];
        p += wv.x * xv.x + wv.y * xv.y + wv.z * xv.z + wv.w * xv.w;
    }
    p += __shfl_xor(p, 1);
    p += __shfl_xor(p, 2);
    if (l == 0) gates[g * (B_ * T_ * H_) + bt * H_ + h] = 1.f / (1.f + __expf(-p));
}

// ---------------------------------------------------------------------------
// Per-chunk: err = M k - v ; u = 2 err (x) k ; omega window-sum (W=16) via
// cumsum ring buffer; S_t = theta_t S_{t-1} - eta_t u'_t (scan). Writes
// chunk_S per step + updates S carry. One block per (b, h, vtile of 8 rows).
// ---------------------------------------------------------------------------
__global__ __launch_bounds__(256) void chunk_s_kernel(const float* __restrict__ kbuf,
                                                      const float* __restrict__ vbuf,
                                                      const float* __restrict__ gates,
                                                      const float* __restrict__ Mc,
                                                      float* __restrict__ Sc,
                                                      float* __restrict__ chunkS,
                                                      int chunk) {
    __shared__ float Kc[CS_][68];
    __shared__ float Mrow[8][68];
    __shared__ float errS[CS_][8];
    __shared__ float thS[CS_], etS[CS_], gmS[CS_];
    int tid = threadIdx.x;
    int idx = blockIdx.x;
    int vt = idx & 7, h = (idx >> 3) & 15, b = idx >> 7;
    int c0t = chunk * CS_;
    {   // stage K chunk (64x64), layout (b,t,h,d)
        int row = tid >> 2, col = (tid & 3) * 16;
        const float* src = &kbuf[((size_t)(b * T_ + c0t + row) * H_ + h) * D_];
        #pragma unroll
        for (int i = 0; i < 4; i++)
            *(float4*)&Kc[row][col + i * 4] = *(const float4*)&src[col + i * 4];
    }
    if (tid < 128) {   // stage M rows vt*8 .. vt*8+7
        int v = tid >> 4, cc = (tid & 15) * 4;
        *(float4*)&Mrow[v][cc] =
            *(const float4*)&Mc[((size_t)(b * H_ + h)) * 4096 + (vt * 8 + v) * 64 + cc];
    }
    if (tid < CS_)           thS[tid] = gates[2 * (B_ * T_ * H_) + (b * T_ + c0t + tid) * H_ + h];
    else if (tid < 2 * CS_)  { int t = tid - CS_;     etS[t] = gates[1 * (B_ * T_ * H_) + (b * T_ + c0t + t) * H_ + h]; }
    else if (tid < 3 * CS_)  { int t = tid - 2 * CS_; gmS[t] = gates[3 * (B_ * T_ * H_) + (b * T_ + c0t + t) * H_ + h]; }
    __syncthreads();
    {   // err[t][vlocal] = Mrow[v] . Kc[t] - v_c
        int t = tid >> 2, v0 = (tid & 3) * 2;
        float s0 = 0.f, s1 = 0.f;
        #pragma unroll
        for (int k = 0; k < 64; k += 4) {
            float4 kv = *(float4*)&Kc[t][k];
            float4 m0 = *(float4*)&Mrow[v0][k];
            float4 m1 = *(float4*)&Mrow[v0 + 1][k];
            s0 += kv.x * m0.x + kv.y * m0.y + kv.z * m0.z + kv.w * m0.w;
            s1 += kv.x * m1.x + kv.y * m1.y + kv.z * m1.z + kv.w * m1.w;
        }
        const float* vp = &vbuf[((size_t)(b * T_ + c0t + t) * H_ + h) * D_ + vt * 8 + v0];
        errS[t][v0]     = s0 - vp[0];
        errS[t][v0 + 1] = s1 - vp[1];
    }
    __syncthreads();
    // scan over the 64 steps; each thread owns 2 matrix elements
    int vl = tid >> 5;            // 0..7 local row
    int kk = (tid & 31) * 2;      // 0..62 col pair
    size_t sIdx = ((size_t)(b * H_ + h)) * 4096 + (vt * 8 + vl) * 64 + kk;
    float S0 = Sc[sIdx], S1 = Sc[sIdx + 1];
    float ring0[16] = {}, ring1[16] = {};
    float cum0 = 0.f, cum1 = 0.f;
    for (int cb = 0; cb < 4; ++cb) {
        #pragma unroll
        for (int ci = 0; ci < 16; ++ci) {
            int c = cb * 16 + ci;
            float er = 2.f * errS[c][vl];
            float2 kv = *(float2*)&Kc[c][kk];
            float g = gmS[c];
            cum0 += g * er * kv.x;
            cum1 += g * er * kv.y;
            float uw0 = cum0 - ring0[ci];
            float uw1 = cum1 - ring1[ci];
            ring0[ci] = cum0; ring1[ci] = cum1;
            float th = thS[c], et = etS[c];
            S0 = th * S0 - et * uw0;
            S1 = th * S1 - et * uw1;
            size_t o = ((size_t)((b * H_ + h) * CS_ + c)) * 4096 + (vt * 8 + vl) * 64 + kk;
            *(float2*)&chunkS[o] = make_float2(S0, S1);
        }
    }
    Sc[sIdx] = S0; Sc[sIdx + 1] = S1;
}

// ---------------------------------------------------------------------------
// Polar-Express / Newton-Schulz orthogonalization of one 64x64 matrix per
// block. X <- aX + (b XXt + c XXt XXt) X  ==  aX + b(YX) + c(Y(YX)).
// ---------------------------------------------------------------------------
__global__ __launch_bounds__(256) void polar_kernel(const float* __restrict__ chunkS,
                                                    float* __restrict__ Z) {
    __shared__ float Xs[64][68];
    __shared__ float Ys[64][68];
    __shared__ float Vs[64][68];
    __shared__ float red[4];
    int tid = threadIdx.x;
    size_t base = (size_t)blockIdx.x * 4096;
    int row = tid >> 2, col0 = (tid & 3) * 16;
    float ss = 0.f;
    #pragma unroll
    for (int i = 0; i < 4; i++) {
        float4 v = *(const float4*)&chunkS[base + row * 64 + col0 + i * 4];
        *(float4*)&Xs[row][col0 + i * 4] = v;
        ss += v.x * v.x + v.y * v.y + v.z * v.z + v.w * v.w;
    }
    ss += __shfl_xor(ss, 1);  ss += __shfl_xor(ss, 2);  ss += __shfl_xor(ss, 4);
    ss += __shfl_xor(ss, 8);  ss += __shfl_xor(ss, 16); ss += __shfl_xor(ss, 32);
    if ((tid & 63) == 0) red[tid >> 6] = ss;
    __syncthreads();
    float sc = 1.f / (sqrtf(red[0] + red[1] + red[2] + red[3]) + 1e-7f);
    #pragma unroll
    for (int i = 0; i < 4; i++) {
        float4* p = (float4*)&Xs[row][col0 + i * 4];
        float4 v = *p; v.x *= sc; v.y *= sc; v.z *= sc; v.w *= sc; *p = v;
    }
    __syncthreads();
    int r0 = (tid >> 4) * 4, c0 = (tid & 15) * 4;
    const float na = 3.4445f, nb = -4.7750f, nc = 2.0315f;
    for (int it = 0; it < NS_; ++it) {
        // Y = X X^T
        float acc[4][4] = {};
        #pragma unroll
        for (int k = 0; k < 64; k += 4) {
            float4 av[4], bv[4];
            #pragma unroll
            for (int i = 0; i < 4; i++) av[i] = *(float4*)&Xs[r0 + i][k];
            #pragma unroll
            for (int j = 0; j < 4; j++) bv[j] = *(float4*)&Xs[c0 + j][k];
            #pragma unroll
            for (int i = 0; i < 4; i++)
                #pragma unroll
                for (int j = 0; j < 4; j++)
                    acc[i][j] += av[i].x * bv[j].x + av[i].y * bv[j].y
                               + av[i].z * bv[j].z + av[i].w * bv[j].w;
        }
        #pragma unroll
        for (int i = 0; i < 4; i++)
            #pragma unroll
            for (int j = 0; j < 4; j++) Ys[r0 + i][c0 + j] = acc[i][j];
        __syncthreads();
        // V1 = Y X
        float a2[4][4] = {};
        #pragma unroll
        for (int k = 0; k < 64; k += 4) {
            float4 yv[4];
            #pragma unroll
            for (int i = 0; i < 4; i++) yv[i] = *(float4*)&Ys[r0 + i][k];
            float4 x0 = *(float4*)&Xs[k + 0][c0];
            float4 x1 = *(float4*)&Xs[k + 1][c0];
            float4 x2 = *(float4*)&Xs[k + 2][c0];
            float4 x3 = *(float4*)&Xs[k + 3][c0];
            #pragma unroll
            for (int i = 0; i < 4; i++) {
                a2[i][0] += yv[i].x * x0.x + yv[i].y * x1.x + yv[i].z * x2.x + yv[i].w * x3.x;
                a2[i][1] += yv[i].x * x0.y + yv[i].y * x1.y + yv[i].z * x2.y + yv[i].w * x3.y;
                a2[i][2] += yv[i].x * x0.z + yv[i].y * x1.z + yv[i].z * x2.z + yv[i].w * x3.z;
                a2[i][3] += yv[i].x * x0.w + yv[i].y * x1.w + yv[i].z * x2.w + yv[i].w * x3.w;
            }
        }
        #pragma unroll
        for (int i = 0; i < 4; i++)
            #pragma unroll
            for (int j = 0; j < 4; j++) Vs[r0 + i][c0 + j] = a2[i][j];
        __syncthreads();
        // V2 = Y V1 ; X = a X + b V1 + c V2
        float a3[4][4] = {};
        #pragma unroll
        for (int k = 0; k < 64; k += 4) {
            float4 yv[4];
            #pragma unroll
            for (int i = 0; i < 4; i++) yv[i] = *(float4*)&Ys[r0 + i][k];
            float4 x0 = *(float4*)&Vs[k + 0][c0];
            float4 x1 = *(float4*)&Vs[k + 1][c0];
            float4 x2 = *(float4*)&Vs[k + 2][c0];
            float4 x3 = *(float4*)&Vs[k + 3][c0];
            #pragma unroll
            for (int i = 0; i < 4; i++) {
                a3[i][0] += yv[i].x * x0.x + yv[i].y * x1.x + yv[i].z * x2.x + yv[i].w * x3.x;
                a3[i][1] += yv[i].x * x0.y + yv[i].y * x1.y + yv[i].z * x2.y + yv[i].w * x3.y;
                a3[i][2] += yv[i].x * x0.z + yv[i].y * x1.z + yv[i].z * x2.z + yv[i].w * x3.z;
                a3[i][3] += yv[i].x * x0.w + yv[i].y * x1.w + yv[i].z * x2.w + yv[i].w * x3.w;
            }
        }
        #pragma unroll
        for (int i = 0; i < 4; i++)
            #pragma unroll
            for (int j = 0; j < 4; j++)
                Xs[r0 + i][c0 + j] = na * Xs[r0 + i][c0 + j] + nb * Vs[r0 + i][c0 + j] + nc * a3[i][j];
        __syncthreads();
    }
    #pragma unroll
    for (int i = 0; i < 4; i++)
        *(float4*)&Z[base + row * 64 + col0 + i * 4] = *(float4*)&Xs[row][col0 + i * 4];
}

// ---------------------------------------------------------------------------
// M scan + output: M_t = alpha_t M_{t-1} + Z_t ; y_t = M_t q_t.
// One block per (b, h, vtile of 8 rows); rows of M are independent in the scan.
// ---------------------------------------------------------------------------
__global__ __launch_bounds__(256) void m_y_kernel(const float* __restrict__ Zb,
                                                  const float* __restrict__ qbuf,
                                                  const float* __restrict__ gates,
                                                  float* __restrict__ Mc,
                                                  float* __restrict__ ybuf,
                                                  int chunk) {
    __shared__ float qs[CS_][68];
    __shared__ float alS[CS_];
    int tid = threadIdx.x;
    int idx = blockIdx.x;
    int vt = idx & 7, h = (idx >> 3) & 15, b = idx >> 7;
    int c0t = chunk * CS_;
    {   // stage q chunk
        int row = tid >> 2, col = (tid & 3) * 16;
        const float* src = &qbuf[((size_t)(b * T_ + c0t + row) * H_ + h) * D_];
        #pragma unroll
        for (int i = 0; i < 4; i++)
            *(float4*)&qs[row][col + i * 4] = *(const float4*)&src[col + i * 4];
    }
    if (tid < CS_) alS[tid] = gates[0 * (B_ * T_ * H_) + (b * T_ + c0t + tid) * H_ + h];
    __syncthreads();
    int vl = tid >> 5, k0 = (tid & 31) * 2;
    size_t mIdx = ((size_t)(b * H_ + h)) * 4096 + (vt * 8 + vl) * 64 + k0;
    float M0 = Mc[mIdx], M1 = Mc[mIdx + 1];
    for (int c = 0; c < CS_; c++) {
        float al = alS[c];
        size_t zo = ((size_t)((b * H_ + h) * CS_ + c)) * 4096 + (vt * 8 + vl) * 64 + k0;
        float2 z = *(const float2*)&Zb[zo];
        M0 = al * M0 + z.x;
        M1 = al * M1 + z.y;
        float2 qv = *(float2*)&qs[c][k0];
        float p = M0 * qv.x + M1 * qv.y;
        p += __shfl_xor(p, 1);  p += __shfl_xor(p, 2);  p += __shfl_xor(p, 4);
        p += __shfl_xor(p, 8);  p += __shfl_xor(p, 16);
        if ((tid & 31) == 0)
            ybuf[((size_t)(b * T_ + c0t + c) * H_ + h) * D_ + vt * 8 + vl] = p;
    }
    Mc[mIdx] = M0; Mc[mIdx + 1] = M1;
}

// ---------------------------------------------------------------------------
extern "C" void kernel_launch(void* const* d_in, const int* in_sizes, int n_in,
                              void* d_out, int out_size, void* d_ws, size_t ws_size,
                              hipStream_t stream) {
    (void)in_sizes; (void)n_in; (void)out_size; (void)ws_size;
    const float* x     = (const float*)d_in[0];
    const float* Wq    = (const float*)d_in[1];
    const float* Wk    = (const float*)d_in[2];
    const float* Wv    = (const float*)d_in[3];
    const float* Wproj = (const float*)d_in[4];
    const float* cqw   = (const float*)d_in[5];
    const float* cqb   = (const float*)d_in[6];
    const float* ckw   = (const float*)d_in[7];
    const float* ckb   = (const float*)d_in[8];
    const float* cvw   = (const float*)d_in[9];
    const float* cvb   = (const float*)d_in[10];
    const float* Wa    = (const float*)d_in[11];
    const float* We    = (const float*)d_in[12];
    const float* Wt    = (const float*)d_in[13];
    const float* Wg    = (const float*)d_in[14];

    float* ws  = (float*)d_ws;
    float* Qb  = ws;                      // 4194304 floats  (B,T,C)
    float* Kb  = Qb + 4194304;            // 4194304
    float* Vb  = Kb + 4194304;            // 4194304
    float* Yb  = Vb + 4194304;            // 4194304
    float* Gb  = Yb + 4194304;            // 262144 (4,B,T,H)
    float* Mc  = Gb + 262144;             // 131072 (B,H,D,D)
    float* Sc  = Mc + 131072;             // 131072
    float* CSb = Sc + 131072;             // 8388608 (B,H,CS,D,D) — also GEMM scratch
    float* Zb  = CSb + 8388608;           // 8388608
    float* bufA = CSb;                    // alias: GEMM out scratch (pre-chunk phase)

    // zero M and S carries (contiguous)
    hipMemsetAsync(Mc, 0, 2 * 131072 * sizeof(float), stream);

    dim3 gg(C_ / 64, (B_ * T_) / 64);
    gemm_abt<B_ * T_, C_, C_><<<gg, 256, 0, stream>>>(x, Wq, bufA);
    conv_kernel<<<B_ * T_, 256, 0, stream>>>(bufA, cqw, cqb, Qb, 1);
    gemm_abt<B_ * T_, C_, C_><<<gg, 256, 0, stream>>>(x, Wk, bufA);
    conv_kernel<<<B_ * T_, 256, 0, stream>>>(bufA, ckw, ckb, Kb, 2);
    gemm_abt<B_ * T_, C_, C_><<<gg, 256, 0, stream>>>(x, Wv, bufA);
    conv_kernel<<<B_ * T_, 256, 0, stream>>>(bufA, cvw, cvb, Vb, 0);
    gates_kernel<<<B_ * T_, 256, 0, stream>>>(x, Wa, We, Wt, Wg, Gb);

    for (int ch = 0; ch < NC_; ++ch) {
        chunk_s_kernel<<<B_ * H_ * 8, 256, 0, stream>>>(Kb, Vb, Gb, Mc, Sc, CSb, ch);
        polar_kernel<<<B_ * H_ * CS_, 256, 0, stream>>>(CSb, Zb);
        m_y_kernel<<<B_ * H_ * 8, 256, 0, stream>>>(Zb, Qb, Gb, Mc, Yb, ch);
    }

    gemm_abt<B_ * T_, C_, C_><<<gg, 256, 0, stream>>>(Yb, Wproj, (float*)d_out);
}

// Round 3
// 5998.437 us; speedup vs baseline: 2.3999x; 2.3999x over previous
//
#include <hip/hip_runtime.h>
#include <math.h>

#define B_ 2
#define T_ 2048
#define C_ 1024
#define H_ 16
#define D_ 64
#define CS_ 64
#define NC_ 32
#define NS_ 5

typedef __attribute__((ext_vector_type(8))) short bf16x8;
typedef __attribute__((ext_vector_type(4))) float f32x4;

__device__ inline unsigned short f2bf(float x) {
    unsigned int u = __builtin_bit_cast(unsigned int, x);
    unsigned int r = (u + 0x7fffu + ((u >> 16) & 1u)) >> 16;
    return (unsigned short)r;
}
__device__ inline float bf2f(unsigned short h) {
    unsigned int u = ((unsigned int)h) << 16;
    return __builtin_bit_cast(float, u);
}
// split x into hi + lo bf16 (lo = x - hi, rounded)
__device__ inline void split2(float x, unsigned short& h, unsigned short& l) {
    h = f2bf(x);
    l = f2bf(x - bf2f(h));
}

// ---------------------------------------------------------------------------
// GEMM: out[M][N] = A[M][K] * Bw[N][K]^T
// ---------------------------------------------------------------------------
template<int M, int N, int K>
__global__ __launch_bounds__(256) void gemm_abt(const float* __restrict__ A,
                                                const float* __restrict__ Bw,
                                                float* __restrict__ out) {
    __shared__ float As[64][36];
    __shared__ float Bs[64][36];
    int tid = threadIdx.x;
    int m0 = blockIdx.y * 64, n0 = blockIdx.x * 64;
    int r0 = (tid >> 4) * 4, c0 = (tid & 15) * 4;
    float acc[4][4] = {};
    for (int kt = 0; kt < K; kt += 32) {
        int lr = tid >> 3, lc = (tid & 7) * 4;
        *(float4*)&As[lr][lc]      = *(const float4*)&A[(m0 + lr) * K + kt + lc];
        *(float4*)&As[lr + 32][lc] = *(const float4*)&A[(m0 + lr + 32) * K + kt + lc];
        *(float4*)&Bs[lr][lc]      = *(const float4*)&Bw[(n0 + lr) * K + kt + lc];
        *(float4*)&Bs[lr + 32][lc] = *(const float4*)&Bw[(n0 + lr + 32) * K + kt + lc];
        __syncthreads();
        #pragma unroll
        for (int kk = 0; kk < 32; kk += 4) {
            float4 a4[4], b4[4];
            #pragma unroll
            for (int i = 0; i < 4; i++) a4[i] = *(float4*)&As[r0 + i][kk];
            #pragma unroll
            for (int j = 0; j < 4; j++) b4[j] = *(float4*)&Bs[c0 + j][kk];
            #pragma unroll
            for (int i = 0; i < 4; i++)
                #pragma unroll
                for (int j = 0; j < 4; j++)
                    acc[i][j] += a4[i].x * b4[j].x + a4[i].y * b4[j].y
                               + a4[i].z * b4[j].z + a4[i].w * b4[j].w;
        }
        __syncthreads();
    }
    #pragma unroll
    for (int i = 0; i < 4; i++) {
        float4 o = make_float4(acc[i][0], acc[i][1], acc[i][2], acc[i][3]);
        *(float4*)&out[(m0 + r0 + i) * N + n0 + c0] = o;
    }
}

// ---------------------------------------------------------------------------
// Causal depthwise conv (K=4) + optional per-head RMS norm + optional poly.
// ---------------------------------------------------------------------------
__global__ __launch_bounds__(256) void conv_kernel(const float* __restrict__ xin,
                                                   const float* __restrict__ w,
                                                   const float* __restrict__ bias,
                                                   float* __restrict__ out, int mode) {
    int bt = blockIdx.x;
    int t = bt & (T_ - 1);
    int tid = threadIdx.x;
    int c0 = tid * 4;
    float4 w4[4];
    #pragma unroll
    for (int i = 0; i < 4; i++) w4[i] = *(const float4*)&w[(c0 + i) * 4];
    float4 bi = *(const float4*)&bias[c0];
    float4 xs[4];
    #pragma unroll
    for (int j = 0; j < 4; j++) {
        int tt = t - 3 + j;
        xs[j] = (tt >= 0) ? *(const float4*)&xin[(bt - 3 + j) * C_ + c0]
                          : make_float4(0.f, 0.f, 0.f, 0.f);
    }
    float y0 = bi.x + w4[0].x * xs[0].x + w4[0].y * xs[1].x + w4[0].z * xs[2].x + w4[0].w * xs[3].x;
    float y1 = bi.y + w4[1].x * xs[0].y + w4[1].y * xs[1].y + w4[1].z * xs[2].y + w4[1].w * xs[3].y;
    float y2 = bi.z + w4[2].x * xs[0].z + w4[2].y * xs[1].z + w4[2].z * xs[2].z + w4[2].w * xs[3].z;
    float y3 = bi.w + w4[3].x * xs[0].w + w4[3].y * xs[1].w + w4[3].z * xs[2].w + w4[3].w * xs[3].w;
    if (mode >= 1) {
        float ss = y0 * y0 + y1 * y1 + y2 * y2 + y3 * y3;
        ss += __shfl_xor(ss, 1);
        ss += __shfl_xor(ss, 2);
        ss += __shfl_xor(ss, 4);
        ss += __shfl_xor(ss, 8);
        float sc = rsqrtf(ss * (1.f / 64.f) + 1e-6f);
        y0 *= sc; y1 *= sc; y2 *= sc; y3 *= sc;
        if (mode == 2) {
            y0 += 0.5f * y0 * y0; y1 += 0.5f * y1 * y1;
            y2 += 0.5f * y2 * y2; y3 += 0.5f * y3 * y3;
        }
    }
    *(float4*)&out[bt * C_ + c0] = make_float4(y0, y1, y2, y3);
}

// ---------------------------------------------------------------------------
// Gate projections.
// ---------------------------------------------------------------------------
__global__ __launch_bounds__(256) void gates_kernel(const float* __restrict__ x,
                                                    const float* __restrict__ Wa,
                                                    const float* __restrict__ We,
                                                    const float* __restrict__ Wt,
                                                    const float* __restrict__ Wg,
                                                    float* __restrict__ gates) {
    __shared__ float xs[C_];
    int bt = blockIdx.x, tid = threadIdx.x;
    *(float4*)&xs[tid * 4] = *(const float4*)&x[bt * C_ + tid * 4];
    __syncthreads();
    int dot = tid >> 2, l = tid & 3;
    int g = dot >> 4, h = dot & 15;
    const float* Wp = (g == 0) ? Wa : (g == 1) ? We : (g == 2) ? Wt : Wg;
    const float* Wr = Wp + h * C_;
    float p = 0.f;
    for (int c = l * 4; c < C_; c += 16) {
        float4 wv = *(const float4*)&Wr[c];
        float4 xv = *(const float4*)&xs[c];
        p += wv.x * xv.x + wv.y * xv.y + wv.z * xv.z + wv.w * xv.w;
    }
    p += __shfl_xor(p, 1);
    p += __shfl_xor(p, 2);
    if (l == 0) gates[g * (B_ * T_ * H_) + bt * H_ + h] = 1.f / (1.f + __expf(-p));
}

// ---------------------------------------------------------------------------
// chunk_s: err/omega/theta-scan — unchanged.
// ---------------------------------------------------------------------------
__global__ __launch_bounds__(256) void chunk_s_kernel(const float* __restrict__ kbuf,
                                                      const float* __restrict__ vbuf,
                                                      const float* __restrict__ gates,
                                                      const float* __restrict__ Mc,
                                                      float* __restrict__ Sc,
                                                      float* __restrict__ chunkS,
                                                      int chunk) {
    __shared__ float Kc[CS_][68];
    __shared__ float Mrow[8][68];
    __shared__ float errS[CS_][8];
    __shared__ float thS[CS_], etS[CS_], gmS[CS_];
    int tid = threadIdx.x;
    int idx = blockIdx.x;
    int vt = idx & 7, h = (idx >> 3) & 15, b = idx >> 7;
    int c0t = chunk * CS_;
    {
        int row = tid >> 2, col = (tid & 3) * 16;
        const float* src = &kbuf[((size_t)(b * T_ + c0t + row) * H_ + h) * D_];
        #pragma unroll
        for (int i = 0; i < 4; i++)
            *(float4*)&Kc[row][col + i * 4] = *(const float4*)&src[col + i * 4];
    }
    if (tid < 128) {
        int v = tid >> 4, cc = (tid & 15) * 4;
        *(float4*)&Mrow[v][cc] =
            *(const float4*)&Mc[((size_t)(b * H_ + h)) * 4096 + (vt * 8 + v) * 64 + cc];
    }
    if (tid < CS_)           thS[tid] = gates[2 * (B_ * T_ * H_) + (b * T_ + c0t + tid) * H_ + h];
    else if (tid < 2 * CS_)  { int t = tid - CS_;     etS[t] = gates[1 * (B_ * T_ * H_) + (b * T_ + c0t + t) * H_ + h]; }
    else if (tid < 3 * CS_)  { int t = tid - 2 * CS_; gmS[t] = gates[3 * (B_ * T_ * H_) + (b * T_ + c0t + t) * H_ + h]; }
    __syncthreads();
    {
        int t = tid >> 2, v0 = (tid & 3) * 2;
        float s0 = 0.f, s1 = 0.f;
        #pragma unroll
        for (int k = 0; k < 64; k += 4) {
            float4 kv = *(float4*)&Kc[t][k];
            float4 m0 = *(float4*)&Mrow[v0][k];
            float4 m1 = *(float4*)&Mrow[v0 + 1][k];
            s0 += kv.x * m0.x + kv.y * m0.y + kv.z * m0.z + kv.w * m0.w;
            s1 += kv.x * m1.x + kv.y * m1.y + kv.z * m1.z + kv.w * m1.w;
        }
        const float* vp = &vbuf[((size_t)(b * T_ + c0t + t) * H_ + h) * D_ + vt * 8 + v0];
        errS[t][v0]     = s0 - vp[0];
        errS[t][v0 + 1] = s1 - vp[1];
    }
    __syncthreads();
    int vl = tid >> 5;
    int kk = (tid & 31) * 2;
    size_t sIdx = ((size_t)(b * H_ + h)) * 4096 + (vt * 8 + vl) * 64 + kk;
    float S0 = Sc[sIdx], S1 = Sc[sIdx + 1];
    float ring0[16] = {}, ring1[16] = {};
    float cum0 = 0.f, cum1 = 0.f;
    for (int cb = 0; cb < 4; ++cb) {
        #pragma unroll
        for (int ci = 0; ci < 16; ++ci) {
            int c = cb * 16 + ci;
            float er = 2.f * errS[c][vl];
            float2 kv = *(float2*)&Kc[c][kk];
            float g = gmS[c];
            cum0 += g * er * kv.x;
            cum1 += g * er * kv.y;
            float uw0 = cum0 - ring0[ci];
            float uw1 = cum1 - ring1[ci];
            ring0[ci] = cum0; ring1[ci] = cum1;
            float th = thS[c], et = etS[c];
            S0 = th * S0 - et * uw0;
            S1 = th * S1 - et * uw1;
            size_t o = ((size_t)((b * H_ + h) * CS_ + c)) * 4096 + (vt * 8 + vl) * 64 + kk;
            *(float2*)&chunkS[o] = make_float2(S0, S1);
        }
    }
    Sc[sIdx] = S0; Sc[sIdx + 1] = S1;
}

// ---------------------------------------------------------------------------
// Polar-Express via SPLIT-PRECISION bf16 MFMA (hi+lo pairs, 3 MFMA terms per
// k-step pair: hh + h*lo + lo*h -> operand error ~2^-18 instead of 2^-9).
// One 64x64 matrix per 256-thread block (4 waves); wave w owns rows 16w..16w+15.
// LDS row stride 72 shorts (144B): 16B-aligned, non-pow2 banks.
// A-frag: lane reads A[rb+(lane&15)][k0+(lane>>4)*8 ..+7] (ds_read_b128)
// B-frag: lane reads Bt[cb+(lane&15)][...]; C-frag: col=lane&15,row=(lane>>4)*4+reg.
// ---------------------------------------------------------------------------
__device__ inline bf16x8 ldfrag(const unsigned short* buf, int rb, int cidx, int koff) {
    return *(const bf16x8*)&buf[(rb + cidx) * 72 + koff];
}

// write M (C-layout regs) into row-major hi/lo bufs
__device__ inline void write_rm2(unsigned short* bh, unsigned short* bl,
                                 float (&M)[4][4], int rw, int q, int c) {
    #pragma unroll
    for (int ct = 0; ct < 4; ct++)
        #pragma unroll
        for (int r = 0; r < 4; r++) {
            unsigned short h, l;
            split2(M[ct][r], h, l);
            unsigned int hl = (unsigned int)h | ((unsigned int)l << 16);
            unsigned int nhl = __shfl_xor((int)hl, 1);
            if ((c & 1) == 0) {
                int off = (rw + 4 * q + r) * 72 + 16 * ct + c;
                *(unsigned int*)&bh[off] = (hl & 0xffffu) | ((nhl & 0xffffu) << 16);
                *(unsigned int*)&bl[off] = (hl >> 16) | (nhl & 0xffff0000u);
            }
        }
}

// write M (C-layout regs) transposed into hi/lo bufs
__device__ inline void write_t2(unsigned short* bh, unsigned short* bl,
                                float (&M)[4][4], int rw, int q, int c) {
    #pragma unroll
    for (int ct = 0; ct < 4; ct++) {
        unsigned short h0, l0, h1, l1, h2, l2, h3, l3;
        split2(M[ct][0], h0, l0); split2(M[ct][1], h1, l1);
        split2(M[ct][2], h2, l2); split2(M[ct][3], h3, l3);
        int off = (16 * ct + c) * 72 + rw + 4 * q;
        *(unsigned int*)&bh[off]     = (unsigned int)h0 | ((unsigned int)h1 << 16);
        *(unsigned int*)&bh[off + 2] = (unsigned int)h2 | ((unsigned int)h3 << 16);
        *(unsigned int*)&bl[off]     = (unsigned int)l0 | ((unsigned int)l1 << 16);
        *(unsigned int*)&bl[off + 2] = (unsigned int)l2 | ((unsigned int)l3 << 16);
    }
}

// 6-term split-precision 16x16 tile: A(h,l) x Bt(h,l), two k-halves
__device__ inline f32x4 mm_split(const bf16x8& a0h, const bf16x8& a1h,
                                 const bf16x8& a0l, const bf16x8& a1l,
                                 const unsigned short* Bh, const unsigned short* Bl,
                                 int cb, int c, int q) {
    bf16x8 b0h = ldfrag(Bh, cb, c, q * 8);
    bf16x8 b1h = ldfrag(Bh, cb, c, 32 + q * 8);
    bf16x8 b0l = ldfrag(Bl, cb, c, q * 8);
    bf16x8 b1l = ldfrag(Bl, cb, c, 32 + q * 8);
    f32x4 acc = {0.f, 0.f, 0.f, 0.f};
    acc = __builtin_amdgcn_mfma_f32_16x16x32_bf16(a0h, b0h, acc, 0, 0, 0);
    acc = __builtin_amdgcn_mfma_f32_16x16x32_bf16(a1h, b1h, acc, 0, 0, 0);
    acc = __builtin_amdgcn_mfma_f32_16x16x32_bf16(a0h, b0l, acc, 0, 0, 0);
    acc = __builtin_amdgcn_mfma_f32_16x16x32_bf16(a1h, b1l, acc, 0, 0, 0);
    acc = __builtin_amdgcn_mfma_f32_16x16x32_bf16(a0l, b0h, acc, 0, 0, 0);
    acc = __builtin_amdgcn_mfma_f32_16x16x32_bf16(a1l, b1h, acc, 0, 0, 0);
    return acc;
}

__global__ __launch_bounds__(256) void polar_kernel(const float* __restrict__ chunkS,
                                                    float* __restrict__ Z) {
    __shared__ __align__(16) unsigned short XsH[64 * 72];
    __shared__ __align__(16) unsigned short XsL[64 * 72];
    __shared__ __align__(16) unsigned short XtH[64 * 72];
    __shared__ __align__(16) unsigned short XtL[64 * 72];
    __shared__ __align__(16) unsigned short YsH[64 * 72];
    __shared__ __align__(16) unsigned short YsL[64 * 72];
    __shared__ __align__(16) unsigned short VtH[64 * 72];
    __shared__ __align__(16) unsigned short VtL[64 * 72];
    __shared__ float red[4];
    int tid = threadIdx.x;
    int w = tid >> 6, lane = tid & 63;
    int q = lane >> 4, c = lane & 15;
    int rw = w * 16;
    size_t base = (size_t)blockIdx.x * 4096;

    float Xc[4][4];
    float ss = 0.f;
    #pragma unroll
    for (int ct = 0; ct < 4; ct++)
        #pragma unroll
        for (int r = 0; r < 4; r++) {
            float v = chunkS[base + (size_t)(rw + 4 * q + r) * 64 + 16 * ct + c];
            Xc[ct][r] = v;
            ss += v * v;
        }
    ss += __shfl_xor(ss, 1);  ss += __shfl_xor(ss, 2);  ss += __shfl_xor(ss, 4);
    ss += __shfl_xor(ss, 8);  ss += __shfl_xor(ss, 16); ss += __shfl_xor(ss, 32);
    if (lane == 0) red[w] = ss;
    __syncthreads();
    float sc = 1.f / (sqrtf(red[0] + red[1] + red[2] + red[3]) + 1e-7f);
    #pragma unroll
    for (int ct = 0; ct < 4; ct++)
        #pragma unroll
        for (int r = 0; r < 4; r++) Xc[ct][r] *= sc;
    write_rm2(XsH, XsL, Xc, rw, q, c);
    write_t2(XtH, XtL, Xc, rw, q, c);
    __syncthreads();

    const float na = 3.4445f, nb = -4.7750f, ncf = 2.0315f;
    float V1c[4][4], Yc[4][4];
    for (int it = 0; it < NS_; ++it) {
        // ---- Y = X X^T  (Bt = X row-major) ----
        bf16x8 a0h = ldfrag(XsH, rw, c, q * 8);
        bf16x8 a1h = ldfrag(XsH, rw, c, 32 + q * 8);
        bf16x8 a0l = ldfrag(XsL, rw, c, q * 8);
        bf16x8 a1l = ldfrag(XsL, rw, c, 32 + q * 8);
        #pragma unroll
        for (int ct = 0; ct < 4; ct++) {
            f32x4 acc = mm_split(a0h, a1h, a0l, a1l, XsH, XsL, 16 * ct, c, q);
            #pragma unroll
            for (int r = 0; r < 4; r++) Yc[ct][r] = acc[r];
        }
        write_rm2(YsH, YsL, Yc, rw, q, c);
        __syncthreads();
        // ---- V1 = Y X  (Bt = Xt) ----
        bf16x8 ya0h = ldfrag(YsH, rw, c, q * 8);
        bf16x8 ya1h = ldfrag(YsH, rw, c, 32 + q * 8);
        bf16x8 ya0l = ldfrag(YsL, rw, c, q * 8);
        bf16x8 ya1l = ldfrag(YsL, rw, c, 32 + q * 8);
        #pragma unroll
        for (int ct = 0; ct < 4; ct++) {
            f32x4 acc = mm_split(ya0h, ya1h, ya0l, ya1l, XtH, XtL, 16 * ct, c, q);
            #pragma unroll
            for (int r = 0; r < 4; r++) V1c[ct][r] = acc[r];
        }
        write_t2(VtH, VtL, V1c, rw, q, c);
        __syncthreads();
        // ---- V2 = Y V1  (Bt = Vt) ; X = a X + b V1 + c V2 ----
        #pragma unroll
        for (int ct = 0; ct < 4; ct++) {
            f32x4 acc = mm_split(ya0h, ya1h, ya0l, ya1l, VtH, VtL, 16 * ct, c, q);
            #pragma unroll
            for (int r = 0; r < 4; r++)
                Xc[ct][r] = na * Xc[ct][r] + nb * V1c[ct][r] + ncf * acc[r];
        }
        write_rm2(XsH, XsL, Xc, rw, q, c);
        write_t2(XtH, XtL, Xc, rw, q, c);
        __syncthreads();
    }
    #pragma unroll
    for (int ct = 0; ct < 4; ct++)
        #pragma unroll
        for (int r = 0; r < 4; r++)
            Z[base + (size_t)(rw + 4 * q + r) * 64 + 16 * ct + c] = Xc[ct][r];
}

// ---------------------------------------------------------------------------
// M scan + output — unchanged.
// ---------------------------------------------------------------------------
__global__ __launch_bounds__(256) void m_y_kernel(const float* __restrict__ Zb,
                                                  const float* __restrict__ qbuf,
                                                  const float* __restrict__ gates,
                                                  float* __restrict__ Mc,
                                                  float* __restrict__ ybuf,
                                                  int chunk) {
    __shared__ float qs[CS_][68];
    __shared__ float alS[CS_];
    int tid = threadIdx.x;
    int idx = blockIdx.x;
    int vt = idx & 7, h = (idx >> 3) & 15, b = idx >> 7;
    int c0t = chunk * CS_;
    {
        int row = tid >> 2, col = (tid & 3) * 16;
        const float* src = &qbuf[((size_t)(b * T_ + c0t + row) * H_ + h) * D_];
        #pragma unroll
        for (int i = 0; i < 4; i++)
            *(float4*)&qs[row][col + i * 4] = *(const float4*)&src[col + i * 4];
    }
    if (tid < CS_) alS[tid] = gates[0 * (B_ * T_ * H_) + (b * T_ + c0t + tid) * H_ + h];
    __syncthreads();
    int vl = tid >> 5, k0 = (tid & 31) * 2;
    size_t mIdx = ((size_t)(b * H_ + h)) * 4096 + (vt * 8 + vl) * 64 + k0;
    float M0 = Mc[mIdx], M1 = Mc[mIdx + 1];
    for (int c = 0; c < CS_; c++) {
        float al = alS[c];
        size_t zo = ((size_t)((b * H_ + h) * CS_ + c)) * 4096 + (vt * 8 + vl) * 64 + k0;
        float2 z = *(const float2*)&Zb[zo];
        M0 = al * M0 + z.x;
        M1 = al * M1 + z.y;
        float2 qv = *(float2*)&qs[c][k0];
        float p = M0 * qv.x + M1 * qv.y;
        p += __shfl_xor(p, 1);  p += __shfl_xor(p, 2);  p += __shfl_xor(p, 4);
        p += __shfl_xor(p, 8);  p += __shfl_xor(p, 16);
        if ((tid & 31) == 0)
            ybuf[((size_t)(b * T_ + c0t + c) * H_ + h) * D_ + vt * 8 + vl] = p;
    }
    Mc[mIdx] = M0; Mc[mIdx + 1] = M1;
}

// ---------------------------------------------------------------------------
extern "C" void kernel_launch(void* const* d_in, const int* in_sizes, int n_in,
                              void* d_out, int out_size, void* d_ws, size_t ws_size,
                              hipStream_t stream) {
    (void)in_sizes; (void)n_in; (void)out_size; (void)ws_size;
    const float* x     = (const float*)d_in[0];
    const float* Wq    = (const float*)d_in[1];
    const float* Wk    = (const float*)d_in[2];
    const float* Wv    = (const float*)d_in[3];
    const float* Wproj = (const float*)d_in[4];
    const float* cqw   = (const float*)d_in[5];
    const float* cqb   = (const float*)d_in[6];
    const float* ckw   = (const float*)d_in[7];
    const float* ckb   = (const float*)d_in[8];
    const float* cvw   = (const float*)d_in[9];
    const float* cvb   = (const float*)d_in[10];
    const float* Wa    = (const float*)d_in[11];
    const float* We    = (const float*)d_in[12];
    const float* Wt    = (const float*)d_in[13];
    const float* Wg    = (const float*)d_in[14];

    float* ws  = (float*)d_ws;
    float* Qb  = ws;                      // 4194304 floats  (B,T,C)
    float* Kb  = Qb + 4194304;            // 4194304
    float* Vb  = Kb + 4194304;            // 4194304
    float* Yb  = Vb + 4194304;            // 4194304
    float* Gb  = Yb + 4194304;            // 262144 (4,B,T,H)
    float* Mc  = Gb + 262144;             // 131072 (B,H,D,D)
    float* Sc  = Mc + 131072;             // 131072
    float* CSb = Sc + 131072;             // 8388608 (B,H,CS,D,D) — also GEMM scratch
    float* Zb  = CSb + 8388608;           // 8388608
    float* bufA = CSb;                    // alias: GEMM out scratch (pre-chunk phase)

    hipMemsetAsync(Mc, 0, 2 * 131072 * sizeof(float), stream);

    dim3 gg(C_ / 64, (B_ * T_) / 64);
    gemm_abt<B_ * T_, C_, C_><<<gg, 256, 0, stream>>>(x, Wq, bufA);
    conv_kernel<<<B_ * T_, 256, 0, stream>>>(bufA, cqw, cqb, Qb, 1);
    gemm_abt<B_ * T_, C_, C_><<<gg, 256, 0, stream>>>(x, Wk, bufA);
    conv_kernel<<<B_ * T_, 256, 0, stream>>>(bufA, ckw, ckb, Kb, 2);
    gemm_abt<B_ * T_, C_, C_><<<gg, 256, 0, stream>>>(x, Wv, bufA);
    conv_kernel<<<B_ * T_, 256, 0, stream>>>(bufA, cvw, cvb, Vb, 0);
    gates_kernel<<<B_ * T_, 256, 0, stream>>>(x, Wa, We, Wt, Wg, Gb);

    for (int ch = 0; ch < NC_; ++ch) {
        chunk_s_kernel<<<B_ * H_ * 8, 256, 0, stream>>>(Kb, Vb, Gb, Mc, Sc, CSb, ch);
        polar_kernel<<<B_ * H_ * CS_, 256, 0, stream>>>(CSb, Zb);
        m_y_kernel<<<B_ * H_ * 8, 256, 0, stream>>>(Zb, Qb, Gb, Mc, Yb, ch);
    }

    gemm_abt<B_ * T_, C_, C_><<<gg, 256, 0, stream>>>(Yb, Wproj, (float*)d_out);
}

// Round 5
// 5083.307 us; speedup vs baseline: 2.8319x; 1.1800x over previous
//
#include <hip/hip_runtime.h>
#include <math.h>

#define B_ 2
#define T_ 2048
#define C_ 1024
#define H_ 16
#define D_ 64
#define CS_ 64
#define NC_ 32
#define NS_ 5

typedef __attribute__((ext_vector_type(8))) short bf16x8;
typedef __attribute__((ext_vector_type(4))) float f32x4;

__device__ inline unsigned short f2bf(float x) {
    unsigned int u = __builtin_bit_cast(unsigned int, x);
    unsigned int r = (u + 0x7fffu + ((u >> 16) & 1u)) >> 16;
    return (unsigned short)r;
}
__device__ inline float bf2f(unsigned short h) {
    unsigned int u = ((unsigned int)h) << 16;
    return __builtin_bit_cast(float, u);
}
__device__ inline void split2(float x, unsigned short& h, unsigned short& l) {
    h = f2bf(x);
    l = f2bf(x - bf2f(h));
}

// ---------------------------------------------------------------------------
// split f32 -> (hi, lo) bf16 buffers
// ---------------------------------------------------------------------------
__global__ __launch_bounds__(256) void split_kernel(const float* __restrict__ src,
                                                    unsigned short* __restrict__ hi,
                                                    unsigned short* __restrict__ lo,
                                                    int n) {
    int i = (blockIdx.x * 256 + threadIdx.x) * 4;
    if (i >= n) return;
    float4 v = *(const float4*)&src[i];
    unsigned short h0, l0, h1, l1, h2, l2, h3, l3;
    split2(v.x, h0, l0); split2(v.y, h1, l1);
    split2(v.z, h2, l2); split2(v.w, h3, l3);
    uint2 hv = make_uint2((unsigned)h0 | ((unsigned)h1 << 16), (unsigned)h2 | ((unsigned)h3 << 16));
    uint2 lv = make_uint2((unsigned)l0 | ((unsigned)l1 << 16), (unsigned)l2 | ((unsigned)l3 << 16));
    *(uint2*)&hi[i] = hv;
    *(uint2*)&lo[i] = lv;
}

// ---------------------------------------------------------------------------
// Split-precision bf16 MFMA GEMM: out[M][N] = A[M][K] * Bw[N][K]^T, f32 out.
// A/Bw pre-split into hi/lo bf16 row-major. 128x128 tile, BK=64, 256 threads.
// Wave w: quadrant rows (w>>1)*64, cols (w&1)*64; 4x4 tiles of 16x16.
// 3-term split: hh + h*lo + lo*h. LDS stride 72 shorts (conflict-free, 16B-aligned).
// FIX r4: stage BOTH rows lrow and lrow+64 (full 128-row tile).
// ---------------------------------------------------------------------------
__global__ __launch_bounds__(256, 1) void gemm_split(const unsigned short* __restrict__ Ah,
                                                     const unsigned short* __restrict__ Al,
                                                     const unsigned short* __restrict__ Bh,
                                                     const unsigned short* __restrict__ Bl,
                                                     float* __restrict__ out) {
    __shared__ __align__(16) unsigned short sAh[128 * 72];
    __shared__ __align__(16) unsigned short sAl[128 * 72];
    __shared__ __align__(16) unsigned short sBh[128 * 72];
    __shared__ __align__(16) unsigned short sBl[128 * 72];
    int tid = threadIdx.x;
    int m0 = blockIdx.y * 128, n0 = blockIdx.x * 128;
    int w = tid >> 6, lane = tid & 63, q = lane >> 4, c = lane & 15;
    int mq = (w >> 1) * 64, nq = (w & 1) * 64;
    f32x4 acc[4][4];
    #pragma unroll
    for (int i = 0; i < 4; i++)
        #pragma unroll
        for (int j = 0; j < 4; j++) acc[i][j] = (f32x4){0.f, 0.f, 0.f, 0.f};
    int lrow = tid >> 2, lseg = (tid & 3) * 16;
    for (int kt = 0; kt < C_; kt += 64) {
        #pragma unroll
        for (int rr = 0; rr < 2; rr++) {
            int row = lrow + rr * 64;
            const size_t ga = (size_t)(m0 + row) * C_ + kt + lseg;
            const size_t gb = (size_t)(n0 + row) * C_ + kt + lseg;
            bf16x8 vah0 = *(const bf16x8*)&Ah[ga];
            bf16x8 vah1 = *(const bf16x8*)&Ah[ga + 8];
            bf16x8 val0 = *(const bf16x8*)&Al[ga];
            bf16x8 val1 = *(const bf16x8*)&Al[ga + 8];
            bf16x8 vbh0 = *(const bf16x8*)&Bh[gb];
            bf16x8 vbh1 = *(const bf16x8*)&Bh[gb + 8];
            bf16x8 vbl0 = *(const bf16x8*)&Bl[gb];
            bf16x8 vbl1 = *(const bf16x8*)&Bl[gb + 8];
            *(bf16x8*)&sAh[row * 72 + lseg] = vah0;
            *(bf16x8*)&sAh[row * 72 + lseg + 8] = vah1;
            *(bf16x8*)&sAl[row * 72 + lseg] = val0;
            *(bf16x8*)&sAl[row * 72 + lseg + 8] = val1;
            *(bf16x8*)&sBh[row * 72 + lseg] = vbh0;
            *(bf16x8*)&sBh[row * 72 + lseg + 8] = vbh1;
            *(bf16x8*)&sBl[row * 72 + lseg] = vbl0;
            *(bf16x8*)&sBl[row * 72 + lseg + 8] = vbl1;
        }
        __syncthreads();
        #pragma unroll
        for (int t = 0; t < 2; t++) {
            bf16x8 af[4][2], bfr[4][2];
            #pragma unroll
            for (int i = 0; i < 4; i++) {
                af[i][0] = *(const bf16x8*)&sAh[(mq + 16 * i + c) * 72 + t * 32 + q * 8];
                af[i][1] = *(const bf16x8*)&sAl[(mq + 16 * i + c) * 72 + t * 32 + q * 8];
            }
            #pragma unroll
            for (int j = 0; j < 4; j++) {
                bfr[j][0] = *(const bf16x8*)&sBh[(nq + 16 * j + c) * 72 + t * 32 + q * 8];
                bfr[j][1] = *(const bf16x8*)&sBl[(nq + 16 * j + c) * 72 + t * 32 + q * 8];
            }
            #pragma unroll
            for (int i = 0; i < 4; i++)
                #pragma unroll
                for (int j = 0; j < 4; j++) {
                    acc[i][j] = __builtin_amdgcn_mfma_f32_16x16x32_bf16(af[i][0], bfr[j][0], acc[i][j], 0, 0, 0);
                    acc[i][j] = __builtin_amdgcn_mfma_f32_16x16x32_bf16(af[i][0], bfr[j][1], acc[i][j], 0, 0, 0);
                    acc[i][j] = __builtin_amdgcn_mfma_f32_16x16x32_bf16(af[i][1], bfr[j][0], acc[i][j], 0, 0, 0);
                }
        }
        __syncthreads();
    }
    #pragma unroll
    for (int i = 0; i < 4; i++)
        #pragma unroll
        for (int j = 0; j < 4; j++)
            #pragma unroll
            for (int r = 0; r < 4; r++)
                out[(size_t)(m0 + mq + 16 * i + 4 * q + r) * C_ + n0 + nq + 16 * j + c] = acc[i][j][r];
}

// ---------------------------------------------------------------------------
// Causal depthwise conv (K=4) + optional per-head RMS norm + optional poly.
// ---------------------------------------------------------------------------
__global__ __launch_bounds__(256) void conv_kernel(const float* __restrict__ xin,
                                                   const float* __restrict__ w,
                                                   const float* __restrict__ bias,
                                                   float* __restrict__ out, int mode) {
    int bt = blockIdx.x;
    int t = bt & (T_ - 1);
    int tid = threadIdx.x;
    int c0 = tid * 4;
    float4 w4[4];
    #pragma unroll
    for (int i = 0; i < 4; i++) w4[i] = *(const float4*)&w[(c0 + i) * 4];
    float4 bi = *(const float4*)&bias[c0];
    float4 xs[4];
    #pragma unroll
    for (int j = 0; j < 4; j++) {
        int tt = t - 3 + j;
        xs[j] = (tt >= 0) ? *(const float4*)&xin[(bt - 3 + j) * C_ + c0]
                          : make_float4(0.f, 0.f, 0.f, 0.f);
    }
    float y0 = bi.x + w4[0].x * xs[0].x + w4[0].y * xs[1].x + w4[0].z * xs[2].x + w4[0].w * xs[3].x;
    float y1 = bi.y + w4[1].x * xs[0].y + w4[1].y * xs[1].y + w4[1].z * xs[2].y + w4[1].w * xs[3].y;
    float y2 = bi.z + w4[2].x * xs[0].z + w4[2].y * xs[1].z + w4[2].z * xs[2].z + w4[2].w * xs[3].z;
    float y3 = bi.w + w4[3].x * xs[0].w + w4[3].y * xs[1].w + w4[3].z * xs[2].w + w4[3].w * xs[3].w;
    if (mode >= 1) {
        float ss = y0 * y0 + y1 * y1 + y2 * y2 + y3 * y3;
        ss += __shfl_xor(ss, 1);
        ss += __shfl_xor(ss, 2);
        ss += __shfl_xor(ss, 4);
        ss += __shfl_xor(ss, 8);
        float sc = rsqrtf(ss * (1.f / 64.f) + 1e-6f);
        y0 *= sc; y1 *= sc; y2 *= sc; y3 *= sc;
        if (mode == 2) {
            y0 += 0.5f * y0 * y0; y1 += 0.5f * y1 * y1;
            y2 += 0.5f * y2 * y2; y3 += 0.5f * y3 * y3;
        }
    }
    *(float4*)&out[bt * C_ + c0] = make_float4(y0, y1, y2, y3);
}

// ---------------------------------------------------------------------------
// Gate projections.
// ---------------------------------------------------------------------------
__global__ __launch_bounds__(256) void gates_kernel(const float* __restrict__ x,
                                                    const float* __restrict__ Wa,
                                                    const float* __restrict__ We,
                                                    const float* __restrict__ Wt,
                                                    const float* __restrict__ Wg,
                                                    float* __restrict__ gates) {
    __shared__ float xs[C_];
    int bt = blockIdx.x, tid = threadIdx.x;
    *(float4*)&xs[tid * 4] = *(const float4*)&x[bt * C_ + tid * 4];
    __syncthreads();
    int dot = tid >> 2, l = tid & 3;
    int g = dot >> 4, h = dot & 15;
    const float* Wp = (g == 0) ? Wa : (g == 1) ? We : (g == 2) ? Wt : Wg;
    const float* Wr = Wp + h * C_;
    float p = 0.f;
    for (int c = l * 4; c < C_; c += 16) {
        float4 wv = *(const float4*)&Wr[c];
        float4 xv = *(const float4*)&xs[c];
        p += wv.x * xv.x + wv.y * xv.y + wv.z * xv.z + wv.w * xv.w;
    }
    p += __shfl_xor(p, 1);
    p += __shfl_xor(p, 2);
    if (l == 0) gates[g * (B_ * T_ * H_) + bt * H_ + h] = 1.f / (1.f + __expf(-p));
}

// ---------------------------------------------------------------------------
// chunk_s: standalone (used for chunk 0 only).
// ---------------------------------------------------------------------------
__global__ __launch_bounds__(256) void chunk_s_kernel(const float* __restrict__ kbuf,
                                                      const float* __restrict__ vbuf,
                                                      const float* __restrict__ gates,
                                                      const float* __restrict__ Mc,
                                                      float* __restrict__ Sc,
                                                      float* __restrict__ chunkS,
                                                      int chunk) {
    __shared__ float Kc[CS_][68];
    __shared__ float Mrow[8][68];
    __shared__ float errS[CS_][8];
    __shared__ float thS[CS_], etS[CS_], gmS[CS_];
    int tid = threadIdx.x;
    int idx = blockIdx.x;
    int vt = idx & 7, h = (idx >> 3) & 15, b = idx >> 7;
    int c0t = chunk * CS_;
    {
        int row = tid >> 2, col = (tid & 3) * 16;
        const float* src = &kbuf[((size_t)(b * T_ + c0t + row) * H_ + h) * D_];
        #pragma unroll
        for (int i = 0; i < 4; i++)
            *(float4*)&Kc[row][col + i * 4] = *(const float4*)&src[col + i * 4];
    }
    if (tid < 128) {
        int v = tid >> 4, cc = (tid & 15) * 4;
        *(float4*)&Mrow[v][cc] =
            *(const float4*)&Mc[((size_t)(b * H_ + h)) * 4096 + (vt * 8 + v) * 64 + cc];
    }
    if (tid < CS_)           thS[tid] = gates[2 * (B_ * T_ * H_) + (b * T_ + c0t + tid) * H_ + h];
    else if (tid < 2 * CS_)  { int t = tid - CS_;     etS[t] = gates[1 * (B_ * T_ * H_) + (b * T_ + c0t + t) * H_ + h]; }
    else if (tid < 3 * CS_)  { int t = tid - 2 * CS_; gmS[t] = gates[3 * (B_ * T_ * H_) + (b * T_ + c0t + t) * H_ + h]; }
    __syncthreads();
    {
        int t = tid >> 2, v0 = (tid & 3) * 2;
        float s0 = 0.f, s1 = 0.f;
        #pragma unroll
        for (int k = 0; k < 64; k += 4) {
            float4 kv = *(float4*)&Kc[t][k];
            float4 m0 = *(float4*)&Mrow[v0][k];
            float4 m1 = *(float4*)&Mrow[v0 + 1][k];
            s0 += kv.x * m0.x + kv.y * m0.y + kv.z * m0.z + kv.w * m0.w;
            s1 += kv.x * m1.x + kv.y * m1.y + kv.z * m1.z + kv.w * m1.w;
        }
        const float* vp = &vbuf[((size_t)(b * T_ + c0t + t) * H_ + h) * D_ + vt * 8 + v0];
        errS[t][v0]     = s0 - vp[0];
        errS[t][v0 + 1] = s1 - vp[1];
    }
    __syncthreads();
    int vl = tid >> 5;
    int kk = (tid & 31) * 2;
    size_t sIdx = ((size_t)(b * H_ + h)) * 4096 + (vt * 8 + vl) * 64 + kk;
    float S0 = Sc[sIdx], S1 = Sc[sIdx + 1];
    float ring0[16] = {}, ring1[16] = {};
    float cum0 = 0.f, cum1 = 0.f;
    for (int cb = 0; cb < 4; ++cb) {
        #pragma unroll
        for (int ci = 0; ci < 16; ++ci) {
            int c = cb * 16 + ci;
            float er = 2.f * errS[c][vl];
            float2 kv = *(float2*)&Kc[c][kk];
            float g = gmS[c];
            cum0 += g * er * kv.x;
            cum1 += g * er * kv.y;
            float uw0 = cum0 - ring0[ci];
            float uw1 = cum1 - ring1[ci];
            ring0[ci] = cum0; ring1[ci] = cum1;
            float th = thS[c], et = etS[c];
            S0 = th * S0 - et * uw0;
            S1 = th * S1 - et * uw1;
            size_t o = ((size_t)((b * H_ + h) * CS_ + c)) * 4096 + (vt * 8 + vl) * 64 + kk;
            *(float2*)&chunkS[o] = make_float2(S0, S1);
        }
    }
    Sc[sIdx] = S0; Sc[sIdx + 1] = S1;
}

// ---------------------------------------------------------------------------
// Polar-Express via split-precision bf16 MFMA. 2 barriers/iter (Y round-trip
// is wave-private: wave w writes and reads only rows 16w..16w+15 of Ys).
// ---------------------------------------------------------------------------
__device__ inline bf16x8 ldfrag(const unsigned short* buf, int rb, int cidx, int koff) {
    return *(const bf16x8*)&buf[(rb + cidx) * 72 + koff];
}

__device__ inline void write_rm2(unsigned short* bh, unsigned short* bl,
                                 float (&M)[4][4], int rw, int q, int c) {
    #pragma unroll
    for (int ct = 0; ct < 4; ct++)
        #pragma unroll
        for (int r = 0; r < 4; r++) {
            unsigned short h, l;
            split2(M[ct][r], h, l);
            unsigned int hl = (unsigned int)h | ((unsigned int)l << 16);
            unsigned int nhl = __shfl_xor((int)hl, 1);
            if ((c & 1) == 0) {
                int off = (rw + 4 * q + r) * 72 + 16 * ct + c;
                *(unsigned int*)&bh[off] = (hl & 0xffffu) | ((nhl & 0xffffu) << 16);
                *(unsigned int*)&bl[off] = (hl >> 16) | (nhl & 0xffff0000u);
            }
        }
}

__device__ inline void write_t2(unsigned short* bh, unsigned short* bl,
                                float (&M)[4][4], int rw, int q, int c) {
    #pragma unroll
    for (int ct = 0; ct < 4; ct++) {
        unsigned short h0, l0, h1, l1, h2, l2, h3, l3;
        split2(M[ct][0], h0, l0); split2(M[ct][1], h1, l1);
        split2(M[ct][2], h2, l2); split2(M[ct][3], h3, l3);
        int off = (16 * ct + c) * 72 + rw + 4 * q;
        *(unsigned int*)&bh[off]     = (unsigned int)h0 | ((unsigned int)h1 << 16);
        *(unsigned int*)&bh[off + 2] = (unsigned int)h2 | ((unsigned int)h3 << 16);
        *(unsigned int*)&bl[off]     = (unsigned int)l0 | ((unsigned int)l1 << 16);
        *(unsigned int*)&bl[off + 2] = (unsigned int)l2 | ((unsigned int)l3 << 16);
    }
}

__device__ inline f32x4 mm_split(const bf16x8& a0h, const bf16x8& a1h,
                                 const bf16x8& a0l, const bf16x8& a1l,
                                 const unsigned short* Bh, const unsigned short* Bl,
                                 int cb, int c, int q) {
    bf16x8 b0h = ldfrag(Bh, cb, c, q * 8);
    bf16x8 b1h = ldfrag(Bh, cb, c, 32 + q * 8);
    bf16x8 b0l = ldfrag(Bl, cb, c, q * 8);
    bf16x8 b1l = ldfrag(Bl, cb, c, 32 + q * 8);
    f32x4 acc = {0.f, 0.f, 0.f, 0.f};
    acc = __builtin_amdgcn_mfma_f32_16x16x32_bf16(a0h, b0h, acc, 0, 0, 0);
    acc = __builtin_amdgcn_mfma_f32_16x16x32_bf16(a1h, b1h, acc, 0, 0, 0);
    acc = __builtin_amdgcn_mfma_f32_16x16x32_bf16(a0h, b0l, acc, 0, 0, 0);
    acc = __builtin_amdgcn_mfma_f32_16x16x32_bf16(a1h, b1l, acc, 0, 0, 0);
    acc = __builtin_amdgcn_mfma_f32_16x16x32_bf16(a0l, b0h, acc, 0, 0, 0);
    acc = __builtin_amdgcn_mfma_f32_16x16x32_bf16(a1l, b1h, acc, 0, 0, 0);
    return acc;
}

__global__ __launch_bounds__(256) void polar_kernel(const float* __restrict__ chunkS,
                                                    float* __restrict__ Z) {
    __shared__ __align__(16) unsigned short XsH[64 * 72];
    __shared__ __align__(16) unsigned short XsL[64 * 72];
    __shared__ __align__(16) unsigned short XtH[64 * 72];
    __shared__ __align__(16) unsigned short XtL[64 * 72];
    __shared__ __align__(16) unsigned short YsH[64 * 72];
    __shared__ __align__(16) unsigned short YsL[64 * 72];
    __shared__ __align__(16) unsigned short VtH[64 * 72];
    __shared__ __align__(16) unsigned short VtL[64 * 72];
    __shared__ float red[4];
    int tid = threadIdx.x;
    int w = tid >> 6, lane = tid & 63;
    int q = lane >> 4, c = lane & 15;
    int rw = w * 16;
    size_t base = (size_t)blockIdx.x * 4096;

    float Xc[4][4];
    float ss = 0.f;
    #pragma unroll
    for (int ct = 0; ct < 4; ct++)
        #pragma unroll
        for (int r = 0; r < 4; r++) {
            float v = chunkS[base + (size_t)(rw + 4 * q + r) * 64 + 16 * ct + c];
            Xc[ct][r] = v;
            ss += v * v;
        }
    ss += __shfl_xor(ss, 1);  ss += __shfl_xor(ss, 2);  ss += __shfl_xor(ss, 4);
    ss += __shfl_xor(ss, 8);  ss += __shfl_xor(ss, 16); ss += __shfl_xor(ss, 32);
    if (lane == 0) red[w] = ss;
    __syncthreads();
    float sc = 1.f / (sqrtf(red[0] + red[1] + red[2] + red[3]) + 1e-7f);
    #pragma unroll
    for (int ct = 0; ct < 4; ct++)
        #pragma unroll
        for (int r = 0; r < 4; r++) Xc[ct][r] *= sc;
    write_rm2(XsH, XsL, Xc, rw, q, c);
    write_t2(XtH, XtL, Xc, rw, q, c);
    __syncthreads();

    const float na = 3.4445f, nb = -4.7750f, ncf = 2.0315f;
    float V1c[4][4], Yc[4][4];
    for (int it = 0; it < NS_; ++it) {
        // ---- Y = X X^T (B = X rows). Y rows rw..rw+15 are wave-private. ----
        bf16x8 a0h = ldfrag(XsH, rw, c, q * 8);
        bf16x8 a1h = ldfrag(XsH, rw, c, 32 + q * 8);
        bf16x8 a0l = ldfrag(XsL, rw, c, q * 8);
        bf16x8 a1l = ldfrag(XsL, rw, c, 32 + q * 8);
        #pragma unroll
        for (int ct = 0; ct < 4; ct++) {
            f32x4 acc = mm_split(a0h, a1h, a0l, a1l, XsH, XsL, 16 * ct, c, q);
            #pragma unroll
            for (int r = 0; r < 4; r++) Yc[ct][r] = acc[r];
        }
        write_rm2(YsH, YsL, Yc, rw, q, c);
        // no barrier: same wave reads back only its own rows of Ys
        bf16x8 ya0h = ldfrag(YsH, rw, c, q * 8);
        bf16x8 ya1h = ldfrag(YsH, rw, c, 32 + q * 8);
        bf16x8 ya0l = ldfrag(YsL, rw, c, q * 8);
        bf16x8 ya1l = ldfrag(YsL, rw, c, 32 + q * 8);
        // ---- V1 = Y X (Bt = Xt) ----
        #pragma unroll
        for (int ct = 0; ct < 4; ct++) {
            f32x4 acc = mm_split(ya0h, ya1h, ya0l, ya1l, XtH, XtL, 16 * ct, c, q);
            #pragma unroll
            for (int r = 0; r < 4; r++) V1c[ct][r] = acc[r];
        }
        write_t2(VtH, VtL, V1c, rw, q, c);
        __syncthreads();
        // ---- V2 = Y V1 (Bt = Vt) ; X = a X + b V1 + c V2 ----
        #pragma unroll
        for (int ct = 0; ct < 4; ct++) {
            f32x4 acc = mm_split(ya0h, ya1h, ya0l, ya1l, VtH, VtL, 16 * ct, c, q);
            #pragma unroll
            for (int r = 0; r < 4; r++)
                Xc[ct][r] = na * Xc[ct][r] + nb * V1c[ct][r] + ncf * acc[r];
        }
        if (it != NS_ - 1) {
            write_rm2(XsH, XsL, Xc, rw, q, c);
            write_t2(XtH, XtL, Xc, rw, q, c);
            __syncthreads();
        }
    }
    #pragma unroll
    for (int ct = 0; ct < 4; ct++)
        #pragma unroll
        for (int r = 0; r < 4; r++)
            Z[base + (size_t)(rw + 4 * q + r) * 64 + 16 * ct + c] = Xc[ct][r];
}

// ---------------------------------------------------------------------------
// Fused: m_y for chunk ch (M scan + y output) + chunk_s for chunk ch+1
// (err/omega/theta-scan), M carried in registers between the two phases.
// ---------------------------------------------------------------------------
__global__ __launch_bounds__(256) void fused_my_cs(const float* __restrict__ Zb,
                                                   const float* __restrict__ qbuf,
                                                   const float* __restrict__ kbuf,
                                                   const float* __restrict__ vbuf,
                                                   const float* __restrict__ gates,
                                                   float* __restrict__ Mc,
                                                   float* __restrict__ Sc,
                                                   float* __restrict__ chunkS,
                                                   float* __restrict__ ybuf,
                                                   int chunk) {
    __shared__ float buf[CS_][68];     // q chunk, then K chunk
    __shared__ float Mrow[8][68];
    __shared__ float errS[CS_][8];
    __shared__ float alS[CS_], thS[CS_], etS[CS_], gmS[CS_];
    int tid = threadIdx.x, idx = blockIdx.x;
    int vt = idx & 7, h = (idx >> 3) & 15, b = idx >> 7;
    int c0t = chunk * CS_;
    {   // stage q chunk
        int row = tid >> 2, col = (tid & 3) * 16;
        const float* src = &qbuf[((size_t)(b * T_ + c0t + row) * H_ + h) * D_];
        #pragma unroll
        for (int i = 0; i < 4; i++)
            *(float4*)&buf[row][col + i * 4] = *(const float4*)&src[col + i * 4];
    }
    if (tid < CS_) alS[tid] = gates[0 * (B_ * T_ * H_) + (b * T_ + c0t + tid) * H_ + h];
    __syncthreads();
    int vl = tid >> 5, k0 = (tid & 31) * 2;
    size_t mIdx = ((size_t)(b * H_ + h)) * 4096 + (vt * 8 + vl) * 64 + k0;
    float M0 = Mc[mIdx], M1 = Mc[mIdx + 1];
    for (int c = 0; c < CS_; c++) {
        float al = alS[c];
        size_t zo = ((size_t)((b * H_ + h) * CS_ + c)) * 4096 + (vt * 8 + vl) * 64 + k0;
        float2 z = *(const float2*)&Zb[zo];
        M0 = al * M0 + z.x;
        M1 = al * M1 + z.y;
        float2 qv = *(float2*)&buf[c][k0];
        float p = M0 * qv.x + M1 * qv.y;
        p += __shfl_xor(p, 1);  p += __shfl_xor(p, 2);  p += __shfl_xor(p, 4);
        p += __shfl_xor(p, 8);  p += __shfl_xor(p, 16);
        if ((tid & 31) == 0)
            ybuf[((size_t)(b * T_ + c0t + c) * H_ + h) * D_ + vt * 8 + vl] = p;
    }
    Mc[mIdx] = M0; Mc[mIdx + 1] = M1;
    if (chunk + 1 >= NC_) return;
    int c1t = c0t + CS_;
    __syncthreads();   // everyone done with buf (q)
    Mrow[vl][k0] = M0; Mrow[vl][k0 + 1] = M1;
    {   // stage K chunk ch+1
        int row = tid >> 2, col = (tid & 3) * 16;
        const float* src = &kbuf[((size_t)(b * T_ + c1t + row) * H_ + h) * D_];
        #pragma unroll
        for (int i = 0; i < 4; i++)
            *(float4*)&buf[row][col + i * 4] = *(const float4*)&src[col + i * 4];
    }
    if (tid < CS_)           thS[tid] = gates[2 * (B_ * T_ * H_) + (b * T_ + c1t + tid) * H_ + h];
    else if (tid < 2 * CS_)  { int t = tid - CS_;     etS[t] = gates[1 * (B_ * T_ * H_) + (b * T_ + c1t + t) * H_ + h]; }
    else if (tid < 3 * CS_)  { int t = tid - 2 * CS_; gmS[t] = gates[3 * (B_ * T_ * H_) + (b * T_ + c1t + t) * H_ + h]; }
    __syncthreads();
    {   // err[t][vlocal] = M . k - v
        int t = tid >> 2, v0 = (tid & 3) * 2;
        float s0 = 0.f, s1 = 0.f;
        #pragma unroll
        for (int k = 0; k < 64; k += 4) {
            float4 kv = *(float4*)&buf[t][k];
            float4 m0v = *(float4*)&Mrow[v0][k];
            float4 m1v = *(float4*)&Mrow[v0 + 1][k];
            s0 += kv.x * m0v.x + kv.y * m0v.y + kv.z * m0v.z + kv.w * m0v.w;
            s1 += kv.x * m1v.x + kv.y * m1v.y + kv.z * m1v.z + kv.w * m1v.w;
        }
        const float* vp = &vbuf[((size_t)(b * T_ + c1t + t) * H_ + h) * D_ + vt * 8 + v0];
        errS[t][v0]     = s0 - vp[0];
        errS[t][v0 + 1] = s1 - vp[1];
    }
    __syncthreads();
    float S0 = Sc[mIdx], S1 = Sc[mIdx + 1];
    float ring0[16] = {}, ring1[16] = {};
    float cum0 = 0.f, cum1 = 0.f;
    for (int cb = 0; cb < 4; ++cb) {
        #pragma unroll
        for (int ci = 0; ci < 16; ++ci) {
            int cc = cb * 16 + ci;
            float er = 2.f * errS[cc][vl];
            float2 kv = *(float2*)&buf[cc][k0];
            float g = gmS[cc];
            cum0 += g * er * kv.x;
            cum1 += g * er * kv.y;
            float uw0 = cum0 - ring0[ci];
            float uw1 = cum1 - ring1[ci];
            ring0[ci] = cum0; ring1[ci] = cum1;
            float th = thS[cc], et = etS[cc];
            S0 = th * S0 - et * uw0;
            S1 = th * S1 - et * uw1;
            size_t o = ((size_t)((b * H_ + h) * CS_ + cc)) * 4096 + (vt * 8 + vl) * 64 + k0;
            *(float2*)&chunkS[o] = make_float2(S0, S1);
        }
    }
    Sc[mIdx] = S0; Sc[mIdx + 1] = S1;
}

// ---------------------------------------------------------------------------
extern "C" void kernel_launch(void* const* d_in, const int* in_sizes, int n_in,
                              void* d_out, int out_size, void* d_ws, size_t ws_size,
                              hipStream_t stream) {
    (void)in_sizes; (void)n_in; (void)out_size; (void)ws_size;
    const float* x     = (const float*)d_in[0];
    const float* Wq    = (const float*)d_in[1];
    const float* Wk    = (const float*)d_in[2];
    const float* Wv    = (const float*)d_in[3];
    const float* Wproj = (const float*)d_in[4];
    const float* cqw   = (const float*)d_in[5];
    const float* cqb   = (const float*)d_in[6];
    const float* ckw   = (const float*)d_in[7];
    const float* ckb   = (const float*)d_in[8];
    const float* cvw   = (const float*)d_in[9];
    const float* cvb   = (const float*)d_in[10];
    const float* Wa    = (const float*)d_in[11];
    const float* We    = (const float*)d_in[12];
    const float* Wt    = (const float*)d_in[13];
    const float* Wg    = (const float*)d_in[14];

    float* ws  = (float*)d_ws;
    float* Qb  = ws;                      // 4194304 floats (B,T,C)
    float* Kb  = Qb + 4194304;
    float* Vb  = Kb + 4194304;
    float* Yb  = Vb + 4194304;
    float* Gb  = Yb + 4194304;            // 262144 (4,B,T,H)
    float* Mc  = Gb + 262144;             // 131072 (B,H,D,D)
    float* Sc  = Mc + 131072;             // 131072
    float* CSb = Sc + 131072;             // 8388608 (B,H,CS,D,D)
    float* Zb  = CSb + 8388608;           // 8388608
    // aliases: split bf16 buffers live in CSb (dead outside the chunk loop);
    // f32 GEMM scratch lives in Zb (dead until first polar).
    unsigned short* su = (unsigned short*)CSb;
    unsigned short* xh  = su;
    unsigned short* xl  = su + 4194304;
    unsigned short* Wqh = su + 8388608,  *Wql = su + 9437184;
    unsigned short* Wkh = su + 10485760, *Wkl = su + 11534336;
    unsigned short* Wvh = su + 12582912, *Wvl = su + 13631488;
    float* bufA = Zb;

    hipMemsetAsync(Mc, 0, 2 * 131072 * sizeof(float), stream);

    // pre-split GEMM operands to hi/lo bf16
    split_kernel<<<4096, 256, 0, stream>>>(x, xh, xl, 4194304);
    split_kernel<<<1024, 256, 0, stream>>>(Wq, Wqh, Wql, 1048576);
    split_kernel<<<1024, 256, 0, stream>>>(Wk, Wkh, Wkl, 1048576);
    split_kernel<<<1024, 256, 0, stream>>>(Wv, Wvh, Wvl, 1048576);

    dim3 gs(C_ / 128, (B_ * T_) / 128);
    gemm_split<<<gs, 256, 0, stream>>>(xh, xl, Wqh, Wql, bufA);
    conv_kernel<<<B_ * T_, 256, 0, stream>>>(bufA, cqw, cqb, Qb, 1);
    gemm_split<<<gs, 256, 0, stream>>>(xh, xl, Wkh, Wkl, bufA);
    conv_kernel<<<B_ * T_, 256, 0, stream>>>(bufA, ckw, ckb, Kb, 2);
    gemm_split<<<gs, 256, 0, stream>>>(xh, xl, Wvh, Wvl, bufA);
    conv_kernel<<<B_ * T_, 256, 0, stream>>>(bufA, cvw, cvb, Vb, 0);
    gates_kernel<<<B_ * T_, 256, 0, stream>>>(x, Wa, We, Wt, Wg, Gb);

    chunk_s_kernel<<<B_ * H_ * 8, 256, 0, stream>>>(Kb, Vb, Gb, Mc, Sc, CSb, 0);
    for (int ch = 0; ch < NC_; ++ch) {
        polar_kernel<<<B_ * H_ * CS_, 256, 0, stream>>>(CSb, Zb);
        fused_my_cs<<<B_ * H_ * 8, 256, 0, stream>>>(Zb, Qb, Kb, Vb, Gb, Mc, Sc, CSb, Yb, ch);
    }

    // final projection: split Yb and Wproj into (now dead) CSb scratch
    unsigned short* Ybh = su, *Ybl = su + 4194304;
    unsigned short* Wph = su + 8388608, *Wpl = su + 9437184;
    split_kernel<<<4096, 256, 0, stream>>>(Yb, Ybh, Ybl, 4194304);
    split_kernel<<<1024, 256, 0, stream>>>(Wproj, Wph, Wpl, 1048576);
    gemm_split<<<gs, 256, 0, stream>>>(Ybh, Ybl, Wph, Wpl, (float*)d_out);
}

// Round 6
// 4235.563 us; speedup vs baseline: 3.3987x; 1.2001x over previous
//
#include <hip/hip_runtime.h>
#include <math.h>

#define B_ 2
#define T_ 2048
#define C_ 1024
#define H_ 16
#define D_ 64
#define CS_ 64
#define NC_ 32
#define NS_ 5
#define IST 136   // interleaved row stride in shorts (64 elems * 2 + 8 pad; 16B-aligned)

typedef __attribute__((ext_vector_type(8))) short bf16x8;
typedef __attribute__((ext_vector_type(4))) float f32x4;

__device__ inline unsigned short f2bf(float x) {
    unsigned int u = __builtin_bit_cast(unsigned int, x);
    unsigned int r = (u + 0x7fffu + ((u >> 16) & 1u)) >> 16;
    return (unsigned short)r;
}
__device__ inline float bf2f(unsigned short h) {
    unsigned int u = ((unsigned int)h) << 16;
    return __builtin_bit_cast(float, u);
}
__device__ inline void split2(float x, unsigned short& h, unsigned short& l) {
    h = f2bf(x);
    l = f2bf(x - bf2f(h));
}

// ---------------------------------------------------------------------------
// split f32 -> (hi, lo) bf16 buffers
// ---------------------------------------------------------------------------
__global__ __launch_bounds__(256) void split_kernel(const float* __restrict__ src,
                                                    unsigned short* __restrict__ hi,
                                                    unsigned short* __restrict__ lo,
                                                    int n) {
    int i = (blockIdx.x * 256 + threadIdx.x) * 4;
    if (i >= n) return;
    float4 v = *(const float4*)&src[i];
    unsigned short h0, l0, h1, l1, h2, l2, h3, l3;
    split2(v.x, h0, l0); split2(v.y, h1, l1);
    split2(v.z, h2, l2); split2(v.w, h3, l3);
    uint2 hv = make_uint2((unsigned)h0 | ((unsigned)h1 << 16), (unsigned)h2 | ((unsigned)h3 << 16));
    uint2 lv = make_uint2((unsigned)l0 | ((unsigned)l1 << 16), (unsigned)l2 | ((unsigned)l3 << 16));
    *(uint2*)&hi[i] = hv;
    *(uint2*)&lo[i] = lv;
}

// ---------------------------------------------------------------------------
// Split-precision bf16 MFMA GEMM (unchanged from round 5).
// ---------------------------------------------------------------------------
__global__ __launch_bounds__(256, 1) void gemm_split(const unsigned short* __restrict__ Ah,
                                                     const unsigned short* __restrict__ Al,
                                                     const unsigned short* __restrict__ Bh,
                                                     const unsigned short* __restrict__ Bl,
                                                     float* __restrict__ out) {
    __shared__ __align__(16) unsigned short sAh[128 * 72];
    __shared__ __align__(16) unsigned short sAl[128 * 72];
    __shared__ __align__(16) unsigned short sBh[128 * 72];
    __shared__ __align__(16) unsigned short sBl[128 * 72];
    int tid = threadIdx.x;
    int m0 = blockIdx.y * 128, n0 = blockIdx.x * 128;
    int w = tid >> 6, lane = tid & 63, q = lane >> 4, c = lane & 15;
    int mq = (w >> 1) * 64, nq = (w & 1) * 64;
    f32x4 acc[4][4];
    #pragma unroll
    for (int i = 0; i < 4; i++)
        #pragma unroll
        for (int j = 0; j < 4; j++) acc[i][j] = (f32x4){0.f, 0.f, 0.f, 0.f};
    int lrow = tid >> 2, lseg = (tid & 3) * 16;
    for (int kt = 0; kt < C_; kt += 64) {
        #pragma unroll
        for (int rr = 0; rr < 2; rr++) {
            int row = lrow + rr * 64;
            const size_t ga = (size_t)(m0 + row) * C_ + kt + lseg;
            const size_t gb = (size_t)(n0 + row) * C_ + kt + lseg;
            bf16x8 vah0 = *(const bf16x8*)&Ah[ga];
            bf16x8 vah1 = *(const bf16x8*)&Ah[ga + 8];
            bf16x8 val0 = *(const bf16x8*)&Al[ga];
            bf16x8 val1 = *(const bf16x8*)&Al[ga + 8];
            bf16x8 vbh0 = *(const bf16x8*)&Bh[gb];
            bf16x8 vbh1 = *(const bf16x8*)&Bh[gb + 8];
            bf16x8 vbl0 = *(const bf16x8*)&Bl[gb];
            bf16x8 vbl1 = *(const bf16x8*)&Bl[gb + 8];
            *(bf16x8*)&sAh[row * 72 + lseg] = vah0;
            *(bf16x8*)&sAh[row * 72 + lseg + 8] = vah1;
            *(bf16x8*)&sAl[row * 72 + lseg] = val0;
            *(bf16x8*)&sAl[row * 72 + lseg + 8] = val1;
            *(bf16x8*)&sBh[row * 72 + lseg] = vbh0;
            *(bf16x8*)&sBh[row * 72 + lseg + 8] = vbh1;
            *(bf16x8*)&sBl[row * 72 + lseg] = vbl0;
            *(bf16x8*)&sBl[row * 72 + lseg + 8] = vbl1;
        }
        __syncthreads();
        #pragma unroll
        for (int t = 0; t < 2; t++) {
            bf16x8 af[4][2], bfr[4][2];
            #pragma unroll
            for (int i = 0; i < 4; i++) {
                af[i][0] = *(const bf16x8*)&sAh[(mq + 16 * i + c) * 72 + t * 32 + q * 8];
                af[i][1] = *(const bf16x8*)&sAl[(mq + 16 * i + c) * 72 + t * 32 + q * 8];
            }
            #pragma unroll
            for (int j = 0; j < 4; j++) {
                bfr[j][0] = *(const bf16x8*)&sBh[(nq + 16 * j + c) * 72 + t * 32 + q * 8];
                bfr[j][1] = *(const bf16x8*)&sBl[(nq + 16 * j + c) * 72 + t * 32 + q * 8];
            }
            #pragma unroll
            for (int i = 0; i < 4; i++)
                #pragma unroll
                for (int j = 0; j < 4; j++) {
                    acc[i][j] = __builtin_amdgcn_mfma_f32_16x16x32_bf16(af[i][0], bfr[j][0], acc[i][j], 0, 0, 0);
                    acc[i][j] = __builtin_amdgcn_mfma_f32_16x16x32_bf16(af[i][0], bfr[j][1], acc[i][j], 0, 0, 0);
                    acc[i][j] = __builtin_amdgcn_mfma_f32_16x16x32_bf16(af[i][1], bfr[j][0], acc[i][j], 0, 0, 0);
                }
        }
        __syncthreads();
    }
    #pragma unroll
    for (int i = 0; i < 4; i++)
        #pragma unroll
        for (int j = 0; j < 4; j++)
            #pragma unroll
            for (int r = 0; r < 4; r++)
                out[(size_t)(m0 + mq + 16 * i + 4 * q + r) * C_ + n0 + nq + 16 * j + c] = acc[i][j][r];
}

// ---------------------------------------------------------------------------
// Causal depthwise conv (K=4) + optional per-head RMS norm + optional poly.
// ---------------------------------------------------------------------------
__global__ __launch_bounds__(256) void conv_kernel(const float* __restrict__ xin,
                                                   const float* __restrict__ w,
                                                   const float* __restrict__ bias,
                                                   float* __restrict__ out, int mode) {
    int bt = blockIdx.x;
    int t = bt & (T_ - 1);
    int tid = threadIdx.x;
    int c0 = tid * 4;
    float4 w4[4];
    #pragma unroll
    for (int i = 0; i < 4; i++) w4[i] = *(const float4*)&w[(c0 + i) * 4];
    float4 bi = *(const float4*)&bias[c0];
    float4 xs[4];
    #pragma unroll
    for (int j = 0; j < 4; j++) {
        int tt = t - 3 + j;
        xs[j] = (tt >= 0) ? *(const float4*)&xin[(bt - 3 + j) * C_ + c0]
                          : make_float4(0.f, 0.f, 0.f, 0.f);
    }
    float y0 = bi.x + w4[0].x * xs[0].x + w4[0].y * xs[1].x + w4[0].z * xs[2].x + w4[0].w * xs[3].x;
    float y1 = bi.y + w4[1].x * xs[0].y + w4[1].y * xs[1].y + w4[1].z * xs[2].y + w4[1].w * xs[3].y;
    float y2 = bi.z + w4[2].x * xs[0].z + w4[2].y * xs[1].z + w4[2].z * xs[2].z + w4[2].w * xs[3].z;
    float y3 = bi.w + w4[3].x * xs[0].w + w4[3].y * xs[1].w + w4[3].z * xs[2].w + w4[3].w * xs[3].w;
    if (mode >= 1) {
        float ss = y0 * y0 + y1 * y1 + y2 * y2 + y3 * y3;
        ss += __shfl_xor(ss, 1);
        ss += __shfl_xor(ss, 2);
        ss += __shfl_xor(ss, 4);
        ss += __shfl_xor(ss, 8);
        float sc = rsqrtf(ss * (1.f / 64.f) + 1e-6f);
        y0 *= sc; y1 *= sc; y2 *= sc; y3 *= sc;
        if (mode == 2) {
            y0 += 0.5f * y0 * y0; y1 += 0.5f * y1 * y1;
            y2 += 0.5f * y2 * y2; y3 += 0.5f * y3 * y3;
        }
    }
    *(float4*)&out[bt * C_ + c0] = make_float4(y0, y1, y2, y3);
}

// ---------------------------------------------------------------------------
// Gate projections.
// ---------------------------------------------------------------------------
__global__ __launch_bounds__(256) void gates_kernel(const float* __restrict__ x,
                                                    const float* __restrict__ Wa,
                                                    const float* __restrict__ We,
                                                    const float* __restrict__ Wt,
                                                    const float* __restrict__ Wg,
                                                    float* __restrict__ gates) {
    __shared__ float xs[C_];
    int bt = blockIdx.x, tid = threadIdx.x;
    *(float4*)&xs[tid * 4] = *(const float4*)&x[bt * C_ + tid * 4];
    __syncthreads();
    int dot = tid >> 2, l = tid & 3;
    int g = dot >> 4, h = dot & 15;
    const float* Wp = (g == 0) ? Wa : (g == 1) ? We : (g == 2) ? Wt : Wg;
    const float* Wr = Wp + h * C_;
    float p = 0.f;
    for (int c = l * 4; c < C_; c += 16) {
        float4 wv = *(const float4*)&Wr[c];
        float4 xv = *(const float4*)&xs[c];
        p += wv.x * xv.x + wv.y * xv.y + wv.z * xv.z + wv.w * xv.w;
    }
    p += __shfl_xor(p, 1);
    p += __shfl_xor(p, 2);
    if (l == 0) gates[g * (B_ * T_ * H_) + bt * H_ + h] = 1.f / (1.f + __expf(-p));
}

// ---------------------------------------------------------------------------
// chunk_s: standalone (chunk 0 only) — unchanged.
// ---------------------------------------------------------------------------
__global__ __launch_bounds__(256) void chunk_s_kernel(const float* __restrict__ kbuf,
                                                      const float* __restrict__ vbuf,
                                                      const float* __restrict__ gates,
                                                      const float* __restrict__ Mc,
                                                      float* __restrict__ Sc,
                                                      float* __restrict__ chunkS,
                                                      int chunk) {
    __shared__ float Kc[CS_][68];
    __shared__ float Mrow[8][68];
    __shared__ float errS[CS_][8];
    __shared__ float thS[CS_], etS[CS_], gmS[CS_];
    int tid = threadIdx.x;
    int idx = blockIdx.x;
    int vt = idx & 7, h = (idx >> 3) & 15, b = idx >> 7;
    int c0t = chunk * CS_;
    {
        int row = tid >> 2, col = (tid & 3) * 16;
        const float* src = &kbuf[((size_t)(b * T_ + c0t + row) * H_ + h) * D_];
        #pragma unroll
        for (int i = 0; i < 4; i++)
            *(float4*)&Kc[row][col + i * 4] = *(const float4*)&src[col + i * 4];
    }
    if (tid < 128) {
        int v = tid >> 4, cc = (tid & 15) * 4;
        *(float4*)&Mrow[v][cc] =
            *(const float4*)&Mc[((size_t)(b * H_ + h)) * 4096 + (vt * 8 + v) * 64 + cc];
    }
    if (tid < CS_)           thS[tid] = gates[2 * (B_ * T_ * H_) + (b * T_ + c0t + tid) * H_ + h];
    else if (tid < 2 * CS_)  { int t = tid - CS_;     etS[t] = gates[1 * (B_ * T_ * H_) + (b * T_ + c0t + t) * H_ + h]; }
    else if (tid < 3 * CS_)  { int t = tid - 2 * CS_; gmS[t] = gates[3 * (B_ * T_ * H_) + (b * T_ + c0t + t) * H_ + h]; }
    __syncthreads();
    {
        int t = tid >> 2, v0 = (tid & 3) * 2;
        float s0 = 0.f, s1 = 0.f;
        #pragma unroll
        for (int k = 0; k < 64; k += 4) {
            float4 kv = *(float4*)&Kc[t][k];
            float4 m0 = *(float4*)&Mrow[v0][k];
            float4 m1 = *(float4*)&Mrow[v0 + 1][k];
            s0 += kv.x * m0.x + kv.y * m0.y + kv.z * m0.z + kv.w * m0.w;
            s1 += kv.x * m1.x + kv.y * m1.y + kv.z * m1.z + kv.w * m1.w;
        }
        const float* vp = &vbuf[((size_t)(b * T_ + c0t + t) * H_ + h) * D_ + vt * 8 + v0];
        errS[t][v0]     = s0 - vp[0];
        errS[t][v0 + 1] = s1 - vp[1];
    }
    __syncthreads();
    int vl = tid >> 5;
    int kk = (tid & 31) * 2;
    size_t sIdx = ((size_t)(b * H_ + h)) * 4096 + (vt * 8 + vl) * 64 + kk;
    float S0 = Sc[sIdx], S1 = Sc[sIdx + 1];
    float ring0[16] = {}, ring1[16] = {};
    float cum0 = 0.f, cum1 = 0.f;
    for (int cb = 0; cb < 4; ++cb) {
        #pragma unroll
        for (int ci = 0; ci < 16; ++ci) {
            int c = cb * 16 + ci;
            float er = 2.f * errS[c][vl];
            float2 kv = *(float2*)&Kc[c][kk];
            float g = gmS[c];
            cum0 += g * er * kv.x;
            cum1 += g * er * kv.y;
            float uw0 = cum0 - ring0[ci];
            float uw1 = cum1 - ring1[ci];
            ring0[ci] = cum0; ring1[ci] = cum1;
            float th = thS[c], et = etS[c];
            S0 = th * S0 - et * uw0;
            S1 = th * S1 - et * uw1;
            size_t o = ((size_t)((b * H_ + h) * CS_ + c)) * 4096 + (vt * 8 + vl) * 64 + kk;
            *(float2*)&chunkS[o] = make_float2(S0, S1);
        }
    }
    Sc[sIdx] = S0; Sc[sIdx + 1] = S1;
}

// ---------------------------------------------------------------------------
// Polar-Express, interleaved-split bf16 MFMA, 3 LDS buffers -> 3 blocks/CU.
// Element (row,col) of a matrix is stored at buf[row*IST + 2*col]=hi,
// [..+1]=lo. One mfma(a,b) = sum(h.h + l.l); mfma(swap16(a),b) = sum(h.l+l.h)
// -> the two together give the EXACT (h+l)x(h+l) product over 16 orig-k per
// MFMA pair. Structure: Y=X.Xt ; Z2=Y.Y (Yt=Y: row-major B reads) ;
// V1=Y.X, V2=Z2.X (B = Xt rows) ; X' = aX + bV1 + cV2.
// Y buffer is reused for Z2 after a barrier. 4 barriers/iter, 2 on the last.
// ---------------------------------------------------------------------------
__device__ inline bf16x8 swap16(bf16x8 v) {
    union { bf16x8 v8; unsigned int u[4]; } x;
    x.v8 = v;
    #pragma unroll
    for (int i = 0; i < 4; i++) x.u[i] = (x.u[i] >> 16) | (x.u[i] << 16);
    return x.v8;
}
__device__ inline bf16x8 ldI(const unsigned short* buf, int row, int g, int q) {
    return *(const bf16x8*)&buf[row * IST + g * 32 + q * 8];
}
// write C-layout regs M[ct][r] (row rw+4q+r, col 16ct+c) row-major interleaved
__device__ inline void writeRowI(unsigned short* buf, const float (&M)[4][4],
                                 int rw, int q, int c) {
    #pragma unroll
    for (int ct = 0; ct < 4; ct++)
        #pragma unroll
        for (int r = 0; r < 4; r++) {
            unsigned short h, l;
            split2(M[ct][r], h, l);
            *(unsigned int*)&buf[(rw + 4 * q + r) * IST + 2 * (16 * ct + c)] =
                (unsigned)h | ((unsigned)l << 16);
        }
}
// write C-layout regs transposed: element -> buf[col][2*row] as one b128 per ct
__device__ inline void writeColI(unsigned short* buf, const float (&M)[4][4],
                                 int rw, int q, int c) {
    #pragma unroll
    for (int ct = 0; ct < 4; ct++) {
        unsigned int d[4];
        #pragma unroll
        for (int r = 0; r < 4; r++) {
            unsigned short h, l;
            split2(M[ct][r], h, l);
            d[r] = (unsigned)h | ((unsigned)l << 16);
        }
        *(uint4*)&buf[(16 * ct + c) * IST + 2 * (rw + 4 * q)] =
            make_uint4(d[0], d[1], d[2], d[3]);
    }
}
// one 16x16 tile: A frags (a, asw) fixed, B from rows rb.. of interleaved buf
__device__ inline f32x4 mmI(const bf16x8 (&a)[4], const bf16x8 (&as)[4],
                            const unsigned short* B, int rb, int c, int q) {
    f32x4 acc = {0.f, 0.f, 0.f, 0.f};
    #pragma unroll
    for (int g = 0; g < 4; g++) {
        bf16x8 b = ldI(B, rb + c, g, q);
        acc = __builtin_amdgcn_mfma_f32_16x16x32_bf16(a[g], b, acc, 0, 0, 0);
        acc = __builtin_amdgcn_mfma_f32_16x16x32_bf16(as[g], b, acc, 0, 0, 0);
    }
    return acc;
}

__global__ __launch_bounds__(256, 3) void polar_kernel(const float* __restrict__ chunkS,
                                                       float* __restrict__ Z) {
    __shared__ __align__(16) unsigned short Xi[64 * IST];
    __shared__ __align__(16) unsigned short Xti[64 * IST];
    __shared__ __align__(16) unsigned short Yi[64 * IST];
    __shared__ float red[4];
    int tid = threadIdx.x;
    int w = tid >> 6, lane = tid & 63;
    int q = lane >> 4, c = lane & 15;
    int rw = w * 16;
    size_t base = (size_t)blockIdx.x * 4096;

    float Xc[4][4];
    float ss = 0.f;
    #pragma unroll
    for (int ct = 0; ct < 4; ct++)
        #pragma unroll
        for (int r = 0; r < 4; r++) {
            float v = chunkS[base + (size_t)(rw + 4 * q + r) * 64 + 16 * ct + c];
            Xc[ct][r] = v;
            ss += v * v;
        }
    ss += __shfl_xor(ss, 1);  ss += __shfl_xor(ss, 2);  ss += __shfl_xor(ss, 4);
    ss += __shfl_xor(ss, 8);  ss += __shfl_xor(ss, 16); ss += __shfl_xor(ss, 32);
    if (lane == 0) red[w] = ss;
    __syncthreads();
    float sc = 1.f / (sqrtf(red[0] + red[1] + red[2] + red[3]) + 1e-7f);
    #pragma unroll
    for (int ct = 0; ct < 4; ct++)
        #pragma unroll
        for (int r = 0; r < 4; r++) Xc[ct][r] *= sc;
    writeRowI(Xi, Xc, rw, q, c);
    writeColI(Xti, Xc, rw, q, c);
    __syncthreads();

    const float na = 3.4445f, nb = -4.7750f, ncf = 2.0315f;
    for (int it = 0; it < NS_; ++it) {
        bf16x8 a[4], as[4];
        // ---- Phase 1: Y = X Xt  (A = Xi own rows, B = Xi rows) ----
        #pragma unroll
        for (int g = 0; g < 4; g++) { a[g] = ldI(Xi, rw + c, g, q); as[g] = swap16(a[g]); }
        float Yc[4][4];
        #pragma unroll
        for (int ct = 0; ct < 4; ct++) {
            f32x4 acc = mmI(a, as, Xi, 16 * ct, c, q);
            #pragma unroll
            for (int r = 0; r < 4; r++) Yc[ct][r] = acc[r];
        }
        writeRowI(Yi, Yc, rw, q, c);
        __syncthreads();   // b1: Yi complete; all Xi reads done
        // ---- Phase 2: Z2 = Y.Y and V1 = Y.X (A = Yi own rows) ----
        #pragma unroll
        for (int g = 0; g < 4; g++) { a[g] = ldI(Yi, rw + c, g, q); as[g] = swap16(a[g]); }
        float Z2c[4][4], V1c[4][4];
        #pragma unroll
        for (int ct = 0; ct < 4; ct++) {
            f32x4 acc = mmI(a, as, Yi, 16 * ct, c, q);
            #pragma unroll
            for (int r = 0; r < 4; r++) Z2c[ct][r] = acc[r];
        }
        #pragma unroll
        for (int ct = 0; ct < 4; ct++) {
            f32x4 acc = mmI(a, as, Xti, 16 * ct, c, q);
            #pragma unroll
            for (int r = 0; r < 4; r++) V1c[ct][r] = acc[r];
        }
        __syncthreads();   // b2: all Yi reads done -> safe to overwrite with Z2
        // ---- Phase 3: V2 = Z2.X ; X' = aX + bV1 + cV2 ----
        writeRowI(Yi, Z2c, rw, q, c);
        #pragma unroll
        for (int g = 0; g < 4; g++) { a[g] = ldI(Yi, rw + c, g, q); as[g] = swap16(a[g]); }
        #pragma unroll
        for (int ct = 0; ct < 4; ct++) {
            f32x4 acc = mmI(a, as, Xti, 16 * ct, c, q);
            #pragma unroll
            for (int r = 0; r < 4; r++)
                Xc[ct][r] = na * Xc[ct][r] + nb * V1c[ct][r] + ncf * acc[r];
        }
        if (it != NS_ - 1) {
            writeRowI(Xi, Xc, rw, q, c);   // safe: Xi unread since b1
            __syncthreads();               // b3: all Xti reads done
            writeColI(Xti, Xc, rw, q, c);
            __syncthreads();               // b4: X ready for next iter
        }
    }
    #pragma unroll
    for (int ct = 0; ct < 4; ct++)
        #pragma unroll
        for (int r = 0; r < 4; r++)
            Z[base + (size_t)(rw + 4 * q + r) * 64 + 16 * ct + c] = Xc[ct][r];
}

// ---------------------------------------------------------------------------
// Fused: m_y(ch) + chunk_s(ch+1) — unchanged from round 5.
// ---------------------------------------------------------------------------
__global__ __launch_bounds__(256) void fused_my_cs(const float* __restrict__ Zb,
                                                   const float* __restrict__ qbuf,
                                                   const float* __restrict__ kbuf,
                                                   const float* __restrict__ vbuf,
                                                   const float* __restrict__ gates,
                                                   float* __restrict__ Mc,
                                                   float* __restrict__ Sc,
                                                   float* __restrict__ chunkS,
                                                   float* __restrict__ ybuf,
                                                   int chunk) {
    __shared__ float buf[CS_][68];
    __shared__ float Mrow[8][68];
    __shared__ float errS[CS_][8];
    __shared__ float alS[CS_], thS[CS_], etS[CS_], gmS[CS_];
    int tid = threadIdx.x, idx = blockIdx.x;
    int vt = idx & 7, h = (idx >> 3) & 15, b = idx >> 7;
    int c0t = chunk * CS_;
    {
        int row = tid >> 2, col = (tid & 3) * 16;
        const float* src = &qbuf[((size_t)(b * T_ + c0t + row) * H_ + h) * D_];
        #pragma unroll
        for (int i = 0; i < 4; i++)
            *(float4*)&buf[row][col + i * 4] = *(const float4*)&src[col + i * 4];
    }
    if (tid < CS_) alS[tid] = gates[0 * (B_ * T_ * H_) + (b * T_ + c0t + tid) * H_ + h];
    __syncthreads();
    int vl = tid >> 5, k0 = (tid & 31) * 2;
    size_t mIdx = ((size_t)(b * H_ + h)) * 4096 + (vt * 8 + vl) * 64 + k0;
    float M0 = Mc[mIdx], M1 = Mc[mIdx + 1];
    for (int c = 0; c < CS_; c++) {
        float al = alS[c];
        size_t zo = ((size_t)((b * H_ + h) * CS_ + c)) * 4096 + (vt * 8 + vl) * 64 + k0;
        float2 z = *(const float2*)&Zb[zo];
        M0 = al * M0 + z.x;
        M1 = al * M1 + z.y;
        float2 qv = *(float2*)&buf[c][k0];
        float p = M0 * qv.x + M1 * qv.y;
        p += __shfl_xor(p, 1);  p += __shfl_xor(p, 2);  p += __shfl_xor(p, 4);
        p += __shfl_xor(p, 8);  p += __shfl_xor(p, 16);
        if ((tid & 31) == 0)
            ybuf[((size_t)(b * T_ + c0t + c) * H_ + h) * D_ + vt * 8 + vl] = p;
    }
    Mc[mIdx] = M0; Mc[mIdx + 1] = M1;
    if (chunk + 1 >= NC_) return;
    int c1t = c0t + CS_;
    __syncthreads();
    Mrow[vl][k0] = M0; Mrow[vl][k0 + 1] = M1;
    {
        int row = tid >> 2, col = (tid & 3) * 16;
        const float* src = &kbuf[((size_t)(b * T_ + c1t + row) * H_ + h) * D_];
        #pragma unroll
        for (int i = 0; i < 4; i++)
            *(float4*)&buf[row][col + i * 4] = *(const float4*)&src[col + i * 4];
    }
    if (tid < CS_)           thS[tid] = gates[2 * (B_ * T_ * H_) + (b * T_ + c1t + tid) * H_ + h];
    else if (tid < 2 * CS_)  { int t = tid - CS_;     etS[t] = gates[1 * (B_ * T_ * H_) + (b * T_ + c1t + t) * H_ + h]; }
    else if (tid < 3 * CS_)  { int t = tid - 2 * CS_; gmS[t] = gates[3 * (B_ * T_ * H_) + (b * T_ + c1t + t) * H_ + h]; }
    __syncthreads();
    {
        int t = tid >> 2, v0 = (tid & 3) * 2;
        float s0 = 0.f, s1 = 0.f;
        #pragma unroll
        for (int k = 0; k < 64; k += 4) {
            float4 kv = *(float4*)&buf[t][k];
            float4 m0v = *(float4*)&Mrow[v0][k];
            float4 m1v = *(float4*)&Mrow[v0 + 1][k];
            s0 += kv.x * m0v.x + kv.y * m0v.y + kv.z * m0v.z + kv.w * m0v.w;
            s1 += kv.x * m1v.x + kv.y * m1v.y + kv.z * m1v.z + kv.w * m1v.w;
        }
        const float* vp = &vbuf[((size_t)(b * T_ + c1t + t) * H_ + h) * D_ + vt * 8 + v0];
        errS[t][v0]     = s0 - vp[0];
        errS[t][v0 + 1] = s1 - vp[1];
    }
    __syncthreads();
    float S0 = Sc[mIdx], S1 = Sc[mIdx + 1];
    float ring0[16] = {}, ring1[16] = {};
    float cum0 = 0.f, cum1 = 0.f;
    for (int cb = 0; cb < 4; ++cb) {
        #pragma unroll
        for (int ci = 0; ci < 16; ++ci) {
            int cc = cb * 16 + ci;
            float er = 2.f * errS[cc][vl];
            float2 kv = *(float2*)&buf[cc][k0];
            float g = gmS[cc];
            cum0 += g * er * kv.x;
            cum1 += g * er * kv.y;
            float uw0 = cum0 - ring0[ci];
            float uw1 = cum1 - ring1[ci];
            ring0[ci] = cum0; ring1[ci] = cum1;
            float th = thS[cc], et = etS[cc];
            S0 = th * S0 - et * uw0;
            S1 = th * S1 - et * uw1;
            size_t o = ((size_t)((b * H_ + h) * CS_ + cc)) * 4096 + (vt * 8 + vl) * 64 + k0;
            *(float2*)&chunkS[o] = make_float2(S0, S1);
        }
    }
    Sc[mIdx] = S0; Sc[mIdx + 1] = S1;
}

// ---------------------------------------------------------------------------
extern "C" void kernel_launch(void* const* d_in, const int* in_sizes, int n_in,
                              void* d_out, int out_size, void* d_ws, size_t ws_size,
                              hipStream_t stream) {
    (void)in_sizes; (void)n_in; (void)out_size; (void)ws_size;
    const float* x     = (const float*)d_in[0];
    const float* Wq    = (const float*)d_in[1];
    const float* Wk    = (const float*)d_in[2];
    const float* Wv    = (const float*)d_in[3];
    const float* Wproj = (const float*)d_in[4];
    const float* cqw   = (const float*)d_in[5];
    const float* cqb   = (const float*)d_in[6];
    const float* ckw   = (const float*)d_in[7];
    const float* ckb   = (const float*)d_in[8];
    const float* cvw   = (const float*)d_in[9];
    const float* cvb   = (const float*)d_in[10];
    const float* Wa    = (const float*)d_in[11];
    const float* We    = (const float*)d_in[12];
    const float* Wt    = (const float*)d_in[13];
    const float* Wg    = (const float*)d_in[14];

    float* ws  = (float*)d_ws;
    float* Qb  = ws;                      // 4194304 floats (B,T,C)
    float* Kb  = Qb + 4194304;
    float* Vb  = Kb + 4194304;
    float* Yb  = Vb + 4194304;
    float* Gb  = Yb + 4194304;            // 262144 (4,B,T,H)
    float* Mc  = Gb + 262144;             // 131072 (B,H,D,D)
    float* Sc  = Mc + 131072;             // 131072
    float* CSb = Sc + 131072;             // 8388608 (B,H,CS,D,D)
    float* Zb  = CSb + 8388608;           // 8388608
    unsigned short* su = (unsigned short*)CSb;
    unsigned short* xh  = su;
    unsigned short* xl  = su + 4194304;
    unsigned short* Wqh = su + 8388608,  *Wql = su + 9437184;
    unsigned short* Wkh = su + 10485760, *Wkl = su + 11534336;
    unsigned short* Wvh = su + 12582912, *Wvl = su + 13631488;
    float* bufA = Zb;

    hipMemsetAsync(Mc, 0, 2 * 131072 * sizeof(float), stream);

    split_kernel<<<4096, 256, 0, stream>>>(x, xh, xl, 4194304);
    split_kernel<<<1024, 256, 0, stream>>>(Wq, Wqh, Wql, 1048576);
    split_kernel<<<1024, 256, 0, stream>>>(Wk, Wkh, Wkl, 1048576);
    split_kernel<<<1024, 256, 0, stream>>>(Wv, Wvh, Wvl, 1048576);

    dim3 gs(C_ / 128, (B_ * T_) / 128);
    gemm_split<<<gs, 256, 0, stream>>>(xh, xl, Wqh, Wql, bufA);
    conv_kernel<<<B_ * T_, 256, 0, stream>>>(bufA, cqw, cqb, Qb, 1);
    gemm_split<<<gs, 256, 0, stream>>>(xh, xl, Wkh, Wkl, bufA);
    conv_kernel<<<B_ * T_, 256, 0, stream>>>(bufA, ckw, ckb, Kb, 2);
    gemm_split<<<gs, 256, 0, stream>>>(xh, xl, Wvh, Wvl, bufA);
    conv_kernel<<<B_ * T_, 256, 0, stream>>>(bufA, cvw, cvb, Vb, 0);
    gates_kernel<<<B_ * T_, 256, 0, stream>>>(x, Wa, We, Wt, Wg, Gb);

    chunk_s_kernel<<<B_ * H_ * 8, 256, 0, stream>>>(Kb, Vb, Gb, Mc, Sc, CSb, 0);
    for (int ch = 0; ch < NC_; ++ch) {
        polar_kernel<<<B_ * H_ * CS_, 256, 0, stream>>>(CSb, Zb);
        fused_my_cs<<<B_ * H_ * 8, 256, 0, stream>>>(Zb, Qb, Kb, Vb, Gb, Mc, Sc, CSb, Yb, ch);
    }

    unsigned short* Ybh = su, *Ybl = su + 4194304;
    unsigned short* Wph = su + 8388608, *Wpl = su + 9437184;
    split_kernel<<<4096, 256, 0, stream>>>(Yb, Ybh, Ybl, 4194304);
    split_kernel<<<1024, 256, 0, stream>>>(Wproj, Wph, Wpl, 1048576);
    gemm_split<<<gs, 256, 0, stream>>>(Ybh, Ybl, Wph, Wpl, (float*)d_out);
}

// Round 7
// 3631.408 us; speedup vs baseline: 3.9642x; 1.1664x over previous
//
#include <hip/hip_runtime.h>
#include <math.h>

#define B_ 2
#define T_ 2048
#define C_ 1024
#define H_ 16
#define D_ 64
#define CS_ 64
#define NC_ 32
#define NS_ 5
#define IST 136   // interleaved row stride in shorts (64 elems * 2 + 8 pad; 16B-aligned)

typedef __attribute__((ext_vector_type(8))) short bf16x8;
typedef __attribute__((ext_vector_type(4))) float f32x4;

__device__ inline unsigned short f2bf(float x) {
    unsigned int u = __builtin_bit_cast(unsigned int, x);
    unsigned int r = (u + 0x7fffu + ((u >> 16) & 1u)) >> 16;
    return (unsigned short)r;
}
__device__ inline float bf2f(unsigned short h) {
    unsigned int u = ((unsigned int)h) << 16;
    return __builtin_bit_cast(float, u);
}
__device__ inline void split2(float x, unsigned short& h, unsigned short& l) {
    h = f2bf(x);
    l = f2bf(x - bf2f(h));
}

// ---------------------------------------------------------------------------
// split f32 -> (hi, lo) bf16 buffers
// ---------------------------------------------------------------------------
__global__ __launch_bounds__(256) void split_kernel(const float* __restrict__ src,
                                                    unsigned short* __restrict__ hi,
                                                    unsigned short* __restrict__ lo,
                                                    int n) {
    int i = (blockIdx.x * 256 + threadIdx.x) * 4;
    if (i >= n) return;
    float4 v = *(const float4*)&src[i];
    unsigned short h0, l0, h1, l1, h2, l2, h3, l3;
    split2(v.x, h0, l0); split2(v.y, h1, l1);
    split2(v.z, h2, l2); split2(v.w, h3, l3);
    uint2 hv = make_uint2((unsigned)h0 | ((unsigned)h1 << 16), (unsigned)h2 | ((unsigned)h3 << 16));
    uint2 lv = make_uint2((unsigned)l0 | ((unsigned)l1 << 16), (unsigned)l2 | ((unsigned)l3 << 16));
    *(uint2*)&hi[i] = hv;
    *(uint2*)&lo[i] = lv;
}

// ---------------------------------------------------------------------------
// Split-precision bf16 MFMA GEMM (unchanged).
// ---------------------------------------------------------------------------
__global__ __launch_bounds__(256, 1) void gemm_split(const unsigned short* __restrict__ Ah,
                                                     const unsigned short* __restrict__ Al,
                                                     const unsigned short* __restrict__ Bh,
                                                     const unsigned short* __restrict__ Bl,
                                                     float* __restrict__ out) {
    __shared__ __align__(16) unsigned short sAh[128 * 72];
    __shared__ __align__(16) unsigned short sAl[128 * 72];
    __shared__ __align__(16) unsigned short sBh[128 * 72];
    __shared__ __align__(16) unsigned short sBl[128 * 72];
    int tid = threadIdx.x;
    int m0 = blockIdx.y * 128, n0 = blockIdx.x * 128;
    int w = tid >> 6, lane = tid & 63, q = lane >> 4, c = lane & 15;
    int mq = (w >> 1) * 64, nq = (w & 1) * 64;
    f32x4 acc[4][4];
    #pragma unroll
    for (int i = 0; i < 4; i++)
        #pragma unroll
        for (int j = 0; j < 4; j++) acc[i][j] = (f32x4){0.f, 0.f, 0.f, 0.f};
    int lrow = tid >> 2, lseg = (tid & 3) * 16;
    for (int kt = 0; kt < C_; kt += 64) {
        #pragma unroll
        for (int rr = 0; rr < 2; rr++) {
            int row = lrow + rr * 64;
            const size_t ga = (size_t)(m0 + row) * C_ + kt + lseg;
            const size_t gb = (size_t)(n0 + row) * C_ + kt + lseg;
            bf16x8 vah0 = *(const bf16x8*)&Ah[ga];
            bf16x8 vah1 = *(const bf16x8*)&Ah[ga + 8];
            bf16x8 val0 = *(const bf16x8*)&Al[ga];
            bf16x8 val1 = *(const bf16x8*)&Al[ga + 8];
            bf16x8 vbh0 = *(const bf16x8*)&Bh[gb];
            bf16x8 vbh1 = *(const bf16x8*)&Bh[gb + 8];
            bf16x8 vbl0 = *(const bf16x8*)&Bl[gb];
            bf16x8 vbl1 = *(const bf16x8*)&Bl[gb + 8];
            *(bf16x8*)&sAh[row * 72 + lseg] = vah0;
            *(bf16x8*)&sAh[row * 72 + lseg + 8] = vah1;
            *(bf16x8*)&sAl[row * 72 + lseg] = val0;
            *(bf16x8*)&sAl[row * 72 + lseg + 8] = val1;
            *(bf16x8*)&sBh[row * 72 + lseg] = vbh0;
            *(bf16x8*)&sBh[row * 72 + lseg + 8] = vbh1;
            *(bf16x8*)&sBl[row * 72 + lseg] = vbl0;
            *(bf16x8*)&sBl[row * 72 + lseg + 8] = vbl1;
        }
        __syncthreads();
        #pragma unroll
        for (int t = 0; t < 2; t++) {
            bf16x8 af[4][2], bfr[4][2];
            #pragma unroll
            for (int i = 0; i < 4; i++) {
                af[i][0] = *(const bf16x8*)&sAh[(mq + 16 * i + c) * 72 + t * 32 + q * 8];
                af[i][1] = *(const bf16x8*)&sAl[(mq + 16 * i + c) * 72 + t * 32 + q * 8];
            }
            #pragma unroll
            for (int j = 0; j < 4; j++) {
                bfr[j][0] = *(const bf16x8*)&sBh[(nq + 16 * j + c) * 72 + t * 32 + q * 8];
                bfr[j][1] = *(const bf16x8*)&sBl[(nq + 16 * j + c) * 72 + t * 32 + q * 8];
            }
            #pragma unroll
            for (int i = 0; i < 4; i++)
                #pragma unroll
                for (int j = 0; j < 4; j++) {
                    acc[i][j] = __builtin_amdgcn_mfma_f32_16x16x32_bf16(af[i][0], bfr[j][0], acc[i][j], 0, 0, 0);
                    acc[i][j] = __builtin_amdgcn_mfma_f32_16x16x32_bf16(af[i][0], bfr[j][1], acc[i][j], 0, 0, 0);
                    acc[i][j] = __builtin_amdgcn_mfma_f32_16x16x32_bf16(af[i][1], bfr[j][0], acc[i][j], 0, 0, 0);
                }
        }
        __syncthreads();
    }
    #pragma unroll
    for (int i = 0; i < 4; i++)
        #pragma unroll
        for (int j = 0; j < 4; j++)
            #pragma unroll
            for (int r = 0; r < 4; r++)
                out[(size_t)(m0 + mq + 16 * i + 4 * q + r) * C_ + n0 + nq + 16 * j + c] = acc[i][j][r];
}

// ---------------------------------------------------------------------------
// Causal depthwise conv (K=4) + optional per-head RMS norm + optional poly.
// ---------------------------------------------------------------------------
__global__ __launch_bounds__(256) void conv_kernel(const float* __restrict__ xin,
                                                   const float* __restrict__ w,
                                                   const float* __restrict__ bias,
                                                   float* __restrict__ out, int mode) {
    int bt = blockIdx.x;
    int t = bt & (T_ - 1);
    int tid = threadIdx.x;
    int c0 = tid * 4;
    float4 w4[4];
    #pragma unroll
    for (int i = 0; i < 4; i++) w4[i] = *(const float4*)&w[(c0 + i) * 4];
    float4 bi = *(const float4*)&bias[c0];
    float4 xs[4];
    #pragma unroll
    for (int j = 0; j < 4; j++) {
        int tt = t - 3 + j;
        xs[j] = (tt >= 0) ? *(const float4*)&xin[(bt - 3 + j) * C_ + c0]
                          : make_float4(0.f, 0.f, 0.f, 0.f);
    }
    float y0 = bi.x + w4[0].x * xs[0].x + w4[0].y * xs[1].x + w4[0].z * xs[2].x + w4[0].w * xs[3].x;
    float y1 = bi.y + w4[1].x * xs[0].y + w4[1].y * xs[1].y + w4[1].z * xs[2].y + w4[1].w * xs[3].y;
    float y2 = bi.z + w4[2].x * xs[0].z + w4[2].y * xs[1].z + w4[2].z * xs[2].z + w4[2].w * xs[3].z;
    float y3 = bi.w + w4[3].x * xs[0].w + w4[3].y * xs[1].w + w4[3].z * xs[2].w + w4[3].w * xs[3].w;
    if (mode >= 1) {
        float ss = y0 * y0 + y1 * y1 + y2 * y2 + y3 * y3;
        ss += __shfl_xor(ss, 1);
        ss += __shfl_xor(ss, 2);
        ss += __shfl_xor(ss, 4);
        ss += __shfl_xor(ss, 8);
        float sc = rsqrtf(ss * (1.f / 64.f) + 1e-6f);
        y0 *= sc; y1 *= sc; y2 *= sc; y3 *= sc;
        if (mode == 2) {
            y0 += 0.5f * y0 * y0; y1 += 0.5f * y1 * y1;
            y2 += 0.5f * y2 * y2; y3 += 0.5f * y3 * y3;
        }
    }
    *(float4*)&out[bt * C_ + c0] = make_float4(y0, y1, y2, y3);
}

// ---------------------------------------------------------------------------
// Gate projections.
// ---------------------------------------------------------------------------
__global__ __launch_bounds__(256) void gates_kernel(const float* __restrict__ x,
                                                    const float* __restrict__ Wa,
                                                    const float* __restrict__ We,
                                                    const float* __restrict__ Wt,
                                                    const float* __restrict__ Wg,
                                                    float* __restrict__ gates) {
    __shared__ float xs[C_];
    int bt = blockIdx.x, tid = threadIdx.x;
    *(float4*)&xs[tid * 4] = *(const float4*)&x[bt * C_ + tid * 4];
    __syncthreads();
    int dot = tid >> 2, l = tid & 3;
    int g = dot >> 4, h = dot & 15;
    const float* Wp = (g == 0) ? Wa : (g == 1) ? We : (g == 2) ? Wt : Wg;
    const float* Wr = Wp + h * C_;
    float p = 0.f;
    for (int c = l * 4; c < C_; c += 16) {
        float4 wv = *(const float4*)&Wr[c];
        float4 xv = *(const float4*)&xs[c];
        p += wv.x * xv.x + wv.y * xv.y + wv.z * xv.z + wv.w * xv.w;
    }
    p += __shfl_xor(p, 1);
    p += __shfl_xor(p, 2);
    if (l == 0) gates[g * (B_ * T_ * H_) + bt * H_ + h] = 1.f / (1.f + __expf(-p));
}

// ---------------------------------------------------------------------------
// chunk_s: standalone (chunk 0 only) — unchanged.
// ---------------------------------------------------------------------------
__global__ __launch_bounds__(256) void chunk_s_kernel(const float* __restrict__ kbuf,
                                                      const float* __restrict__ vbuf,
                                                      const float* __restrict__ gates,
                                                      const float* __restrict__ Mc,
                                                      float* __restrict__ Sc,
                                                      float* __restrict__ chunkS,
                                                      int chunk) {
    __shared__ float Kc[CS_][68];
    __shared__ float Mrow[8][68];
    __shared__ float errS[CS_][8];
    __shared__ float thS[CS_], etS[CS_], gmS[CS_];
    int tid = threadIdx.x;
    int idx = blockIdx.x;
    int vt = idx & 7, h = (idx >> 3) & 15, b = idx >> 7;
    int c0t = chunk * CS_;
    {
        int row = tid >> 2, col = (tid & 3) * 16;
        const float* src = &kbuf[((size_t)(b * T_ + c0t + row) * H_ + h) * D_];
        #pragma unroll
        for (int i = 0; i < 4; i++)
            *(float4*)&Kc[row][col + i * 4] = *(const float4*)&src[col + i * 4];
    }
    if (tid < 128) {
        int v = tid >> 4, cc = (tid & 15) * 4;
        *(float4*)&Mrow[v][cc] =
            *(const float4*)&Mc[((size_t)(b * H_ + h)) * 4096 + (vt * 8 + v) * 64 + cc];
    }
    if (tid < CS_)           thS[tid] = gates[2 * (B_ * T_ * H_) + (b * T_ + c0t + tid) * H_ + h];
    else if (tid < 2 * CS_)  { int t = tid - CS_;     etS[t] = gates[1 * (B_ * T_ * H_) + (b * T_ + c0t + t) * H_ + h]; }
    else if (tid < 3 * CS_)  { int t = tid - 2 * CS_; gmS[t] = gates[3 * (B_ * T_ * H_) + (b * T_ + c0t + t) * H_ + h]; }
    __syncthreads();
    {
        int t = tid >> 2, v0 = (tid & 3) * 2;
        float s0 = 0.f, s1 = 0.f;
        #pragma unroll
        for (int k = 0; k < 64; k += 4) {
            float4 kv = *(float4*)&Kc[t][k];
            float4 m0 = *(float4*)&Mrow[v0][k];
            float4 m1 = *(float4*)&Mrow[v0 + 1][k];
            s0 += kv.x * m0.x + kv.y * m0.y + kv.z * m0.z + kv.w * m0.w;
            s1 += kv.x * m1.x + kv.y * m1.y + kv.z * m1.z + kv.w * m1.w;
        }
        const float* vp = &vbuf[((size_t)(b * T_ + c0t + t) * H_ + h) * D_ + vt * 8 + v0];
        errS[t][v0]     = s0 - vp[0];
        errS[t][v0 + 1] = s1 - vp[1];
    }
    __syncthreads();
    int vl = tid >> 5;
    int kk = (tid & 31) * 2;
    size_t sIdx = ((size_t)(b * H_ + h)) * 4096 + (vt * 8 + vl) * 64 + kk;
    float S0 = Sc[sIdx], S1 = Sc[sIdx + 1];
    float ring0[16] = {}, ring1[16] = {};
    float cum0 = 0.f, cum1 = 0.f;
    for (int cb = 0; cb < 4; ++cb) {
        #pragma unroll
        for (int ci = 0; ci < 16; ++ci) {
            int c = cb * 16 + ci;
            float er = 2.f * errS[c][vl];
            float2 kv = *(float2*)&Kc[c][kk];
            float g = gmS[c];
            cum0 += g * er * kv.x;
            cum1 += g * er * kv.y;
            float uw0 = cum0 - ring0[ci];
            float uw1 = cum1 - ring1[ci];
            ring0[ci] = cum0; ring1[ci] = cum1;
            float th = thS[c], et = etS[c];
            S0 = th * S0 - et * uw0;
            S1 = th * S1 - et * uw1;
            size_t o = ((size_t)((b * H_ + h) * CS_ + c)) * 4096 + (vt * 8 + vl) * 64 + kk;
            *(float2*)&chunkS[o] = make_float2(S0, S1);
        }
    }
    Sc[sIdx] = S0; Sc[sIdx + 1] = S1;
}

// ---------------------------------------------------------------------------
// Polar-Express, interleaved-split bf16 MFMA, 3-matmul form:
//   Y = X Xt ; Z2 = Y Y ; W = bY + cZ2 (registers) ; X' = aX + W X.
// 96 MFMA + 60 ds_read_b128 per iter per wave, 3 barriers/iter (last iter 2).
// Barrier audit: Xi written pre-b3(i), read in P1(i+1) after b3(i).
// Xti written post-b3(i), read in P3(i+1) which is after b1,b2(i+1). Y/W
// round-trips through Yi are wave-private (rows rw..rw+15).
// ---------------------------------------------------------------------------
__device__ inline bf16x8 swap16(bf16x8 v) {
    union { bf16x8 v8; unsigned int u[4]; } x;
    x.v8 = v;
    #pragma unroll
    for (int i = 0; i < 4; i++) x.u[i] = (x.u[i] >> 16) | (x.u[i] << 16);
    return x.v8;
}
__device__ inline bf16x8 ldI(const unsigned short* buf, int row, int g, int q) {
    return *(const bf16x8*)&buf[row * IST + g * 32 + q * 8];
}
__device__ inline void writeRowI(unsigned short* buf, const float (&M)[4][4],
                                 int rw, int q, int c) {
    #pragma unroll
    for (int ct = 0; ct < 4; ct++)
        #pragma unroll
        for (int r = 0; r < 4; r++) {
            unsigned short h, l;
            split2(M[ct][r], h, l);
            *(unsigned int*)&buf[(rw + 4 * q + r) * IST + 2 * (16 * ct + c)] =
                (unsigned)h | ((unsigned)l << 16);
        }
}
__device__ inline void writeColI(unsigned short* buf, const float (&M)[4][4],
                                 int rw, int q, int c) {
    #pragma unroll
    for (int ct = 0; ct < 4; ct++) {
        unsigned int d[4];
        #pragma unroll
        for (int r = 0; r < 4; r++) {
            unsigned short h, l;
            split2(M[ct][r], h, l);
            d[r] = (unsigned)h | ((unsigned)l << 16);
        }
        *(uint4*)&buf[(16 * ct + c) * IST + 2 * (rw + 4 * q)] =
            make_uint4(d[0], d[1], d[2], d[3]);
    }
}
__device__ inline f32x4 mmI(const bf16x8 (&a)[4], const bf16x8 (&as)[4],
                            const unsigned short* B, int rb, int c, int q) {
    f32x4 acc = {0.f, 0.f, 0.f, 0.f};
    #pragma unroll
    for (int g = 0; g < 4; g++) {
        bf16x8 b = ldI(B, rb + c, g, q);
        acc = __builtin_amdgcn_mfma_f32_16x16x32_bf16(a[g], b, acc, 0, 0, 0);
        acc = __builtin_amdgcn_mfma_f32_16x16x32_bf16(as[g], b, acc, 0, 0, 0);
    }
    return acc;
}

__global__ __launch_bounds__(256, 3) void polar_kernel(const float* __restrict__ chunkS,
                                                       float* __restrict__ Z) {
    __shared__ __align__(16) unsigned short Xi[64 * IST];
    __shared__ __align__(16) unsigned short Xti[64 * IST];
    __shared__ __align__(16) unsigned short Yi[64 * IST];
    __shared__ float red[4];
    int tid = threadIdx.x;
    int w = tid >> 6, lane = tid & 63;
    int q = lane >> 4, c = lane & 15;
    int rw = w * 16;
    size_t base = (size_t)blockIdx.x * 4096;

    float Xc[4][4];
    float ss = 0.f;
    #pragma unroll
    for (int ct = 0; ct < 4; ct++)
        #pragma unroll
        for (int r = 0; r < 4; r++) {
            float v = chunkS[base + (size_t)(rw + 4 * q + r) * 64 + 16 * ct + c];
            Xc[ct][r] = v;
            ss += v * v;
        }
    ss += __shfl_xor(ss, 1);  ss += __shfl_xor(ss, 2);  ss += __shfl_xor(ss, 4);
    ss += __shfl_xor(ss, 8);  ss += __shfl_xor(ss, 16); ss += __shfl_xor(ss, 32);
    if (lane == 0) red[w] = ss;
    __syncthreads();
    float sc = 1.f / (sqrtf(red[0] + red[1] + red[2] + red[3]) + 1e-7f);
    #pragma unroll
    for (int ct = 0; ct < 4; ct++)
        #pragma unroll
        for (int r = 0; r < 4; r++) Xc[ct][r] *= sc;
    writeRowI(Xi, Xc, rw, q, c);
    writeColI(Xti, Xc, rw, q, c);
    __syncthreads();

    const float na = 3.4445f, nb = -4.7750f, ncf = 2.0315f;
    for (int it = 0; it < NS_; ++it) {
        bf16x8 a[4], as[4];
        // ---- P1: Y = X Xt (A = own Xi rows, B = Xi rows) ----
        #pragma unroll
        for (int g = 0; g < 4; g++) { a[g] = ldI(Xi, rw + c, g, q); as[g] = swap16(a[g]); }
        float Yc[4][4];
        #pragma unroll
        for (int ct = 0; ct < 4; ct++) {
            f32x4 acc = mmI(a, as, Xi, 16 * ct, c, q);
            #pragma unroll
            for (int r = 0; r < 4; r++) Yc[ct][r] = acc[r];
        }
        writeRowI(Yi, Yc, rw, q, c);
        __syncthreads();   // b1: Yi complete; all Xi reads done
        // ---- P2: Z2 = Y.Y ; W = b*Y + c*Z2 in regs (own rows) ----
        #pragma unroll
        for (int g = 0; g < 4; g++) { a[g] = ldI(Yi, rw + c, g, q); as[g] = swap16(a[g]); }
        #pragma unroll
        for (int ct = 0; ct < 4; ct++) {
            f32x4 acc = mmI(a, as, Yi, 16 * ct, c, q);
            #pragma unroll
            for (int r = 0; r < 4; r++) Yc[ct][r] = nb * Yc[ct][r] + ncf * acc[r];
        }
        __syncthreads();   // b2: all Yi reads done -> safe to overwrite with W
        // ---- P3: W rows -> Yi (wave-private round-trip) ; V = W.X ----
        writeRowI(Yi, Yc, rw, q, c);
        #pragma unroll
        for (int g = 0; g < 4; g++) { a[g] = ldI(Yi, rw + c, g, q); as[g] = swap16(a[g]); }
        #pragma unroll
        for (int ct = 0; ct < 4; ct++) {
            f32x4 acc = mmI(a, as, Xti, 16 * ct, c, q);
            #pragma unroll
            for (int r = 0; r < 4; r++)
                Xc[ct][r] = na * Xc[ct][r] + acc[r];
        }
        if (it != NS_ - 1) {
            writeRowI(Xi, Xc, rw, q, c);   // Xi unread since b1
            __syncthreads();               // b3: Xti reads done; Xi visible
            writeColI(Xti, Xc, rw, q, c);  // read next iter only after b1,b2
        }
    }
    #pragma unroll
    for (int ct = 0; ct < 4; ct++)
        #pragma unroll
        for (int r = 0; r < 4; r++)
            Z[base + (size_t)(rw + 4 * q + r) * 64 + 16 * ct + c] = Xc[ct][r];
}

// ---------------------------------------------------------------------------
// Fused: m_y(ch) + chunk_s(ch+1), with the Zb load software-pipelined one
// iteration ahead (the serial M-scan otherwise eats full load latency).
// ---------------------------------------------------------------------------
__global__ __launch_bounds__(256) void fused_my_cs(const float* __restrict__ Zb,
                                                   const float* __restrict__ qbuf,
                                                   const float* __restrict__ kbuf,
                                                   const float* __restrict__ vbuf,
                                                   const float* __restrict__ gates,
                                                   float* __restrict__ Mc,
                                                   float* __restrict__ Sc,
                                                   float* __restrict__ chunkS,
                                                   float* __restrict__ ybuf,
                                                   int chunk) {
    __shared__ float buf[CS_][68];
    __shared__ float Mrow[8][68];
    __shared__ float errS[CS_][8];
    __shared__ float alS[CS_], thS[CS_], etS[CS_], gmS[CS_];
    int tid = threadIdx.x, idx = blockIdx.x;
    int vt = idx & 7, h = (idx >> 3) & 15, b = idx >> 7;
    int c0t = chunk * CS_;
    {
        int row = tid >> 2, col = (tid & 3) * 16;
        const float* src = &qbuf[((size_t)(b * T_ + c0t + row) * H_ + h) * D_];
        #pragma unroll
        for (int i = 0; i < 4; i++)
            *(float4*)&buf[row][col + i * 4] = *(const float4*)&src[col + i * 4];
    }
    if (tid < CS_) alS[tid] = gates[0 * (B_ * T_ * H_) + (b * T_ + c0t + tid) * H_ + h];
    __syncthreads();
    int vl = tid >> 5, k0 = (tid & 31) * 2;
    size_t mIdx = ((size_t)(b * H_ + h)) * 4096 + (vt * 8 + vl) * 64 + k0;
    size_t zrow = ((size_t)(b * H_ + h) * CS_) * 4096 + (vt * 8 + vl) * 64 + k0;
    float M0 = Mc[mIdx], M1 = Mc[mIdx + 1];
    float2 z = *(const float2*)&Zb[zrow];
    for (int c = 0; c < CS_; c++) {
        float2 znext = (c + 1 < CS_) ? *(const float2*)&Zb[zrow + (size_t)(c + 1) * 4096]
                                     : make_float2(0.f, 0.f);
        float al = alS[c];
        M0 = al * M0 + z.x;
        M1 = al * M1 + z.y;
        float2 qv = *(float2*)&buf[c][k0];
        float p = M0 * qv.x + M1 * qv.y;
        p += __shfl_xor(p, 1);  p += __shfl_xor(p, 2);  p += __shfl_xor(p, 4);
        p += __shfl_xor(p, 8);  p += __shfl_xor(p, 16);
        if ((tid & 31) == 0)
            ybuf[((size_t)(b * T_ + c0t + c) * H_ + h) * D_ + vt * 8 + vl] = p;
        z = znext;
    }
    Mc[mIdx] = M0; Mc[mIdx + 1] = M1;
    if (chunk + 1 >= NC_) return;
    int c1t = c0t + CS_;
    __syncthreads();
    Mrow[vl][k0] = M0; Mrow[vl][k0 + 1] = M1;
    {
        int row = tid >> 2, col = (tid & 3) * 16;
        const float* src = &kbuf[((size_t)(b * T_ + c1t + row) * H_ + h) * D_];
        #pragma unroll
        for (int i = 0; i < 4; i++)
            *(float4*)&buf[row][col + i * 4] = *(const float4*)&src[col + i * 4];
    }
    if (tid < CS_)           thS[tid] = gates[2 * (B_ * T_ * H_) + (b * T_ + c1t + tid) * H_ + h];
    else if (tid < 2 * CS_)  { int t = tid - CS_;     etS[t] = gates[1 * (B_ * T_ * H_) + (b * T_ + c1t + t) * H_ + h]; }
    else if (tid < 3 * CS_)  { int t = tid - 2 * CS_; gmS[t] = gates[3 * (B_ * T_ * H_) + (b * T_ + c1t + t) * H_ + h]; }
    __syncthreads();
    {
        int t = tid >> 2, v0 = (tid & 3) * 2;
        float s0 = 0.f, s1 = 0.f;
        #pragma unroll
        for (int k = 0; k < 64; k += 4) {
            float4 kv = *(float4*)&buf[t][k];
            float4 m0v = *(float4*)&Mrow[v0][k];
            float4 m1v = *(float4*)&Mrow[v0 + 1][k];
            s0 += kv.x * m0v.x + kv.y * m0v.y + kv.z * m0v.z + kv.w * m0v.w;
            s1 += kv.x * m1v.x + kv.y * m1v.y + kv.z * m1v.z + kv.w * m1v.w;
        }
        const float* vp = &vbuf[((size_t)(b * T_ + c1t + t) * H_ + h) * D_ + vt * 8 + v0];
        errS[t][v0]     = s0 - vp[0];
        errS[t][v0 + 1] = s1 - vp[1];
    }
    __syncthreads();
    float S0 = Sc[mIdx], S1 = Sc[mIdx + 1];
    float ring0[16] = {}, ring1[16] = {};
    float cum0 = 0.f, cum1 = 0.f;
    for (int cb = 0; cb < 4; ++cb) {
        #pragma unroll
        for (int ci = 0; ci < 16; ++ci) {
            int cc = cb * 16 + ci;
            float er = 2.f * errS[cc][vl];
            float2 kv = *(float2*)&buf[cc][k0];
            float g = gmS[cc];
            cum0 += g * er * kv.x;
            cum1 += g * er * kv.y;
            float uw0 = cum0 - ring0[ci];
            float uw1 = cum1 - ring1[ci];
            ring0[ci] = cum0; ring1[ci] = cum1;
            float th = thS[cc], et = etS[cc];
            S0 = th * S0 - et * uw0;
            S1 = th * S1 - et * uw1;
            size_t o = ((size_t)((b * H_ + h) * CS_ + cc)) * 4096 + (vt * 8 + vl) * 64 + k0;
            *(float2*)&chunkS[o] = make_float2(S0, S1);
        }
    }
    Sc[mIdx] = S0; Sc[mIdx + 1] = S1;
}

// ---------------------------------------------------------------------------
extern "C" void kernel_launch(void* const* d_in, const int* in_sizes, int n_in,
                              void* d_out, int out_size, void* d_ws, size_t ws_size,
                              hipStream_t stream) {
    (void)in_sizes; (void)n_in; (void)out_size; (void)ws_size;
    const float* x     = (const float*)d_in[0];
    const float* Wq    = (const float*)d_in[1];
    const float* Wk    = (const float*)d_in[2];
    const float* Wv    = (const float*)d_in[3];
    const float* Wproj = (const float*)d_in[4];
    const float* cqw   = (const float*)d_in[5];
    const float* cqb   = (const float*)d_in[6];
    const float* ckw   = (const float*)d_in[7];
    const float* ckb   = (const float*)d_in[8];
    const float* cvw   = (const float*)d_in[9];
    const float* cvb   = (const float*)d_in[10];
    const float* Wa    = (const float*)d_in[11];
    const float* We    = (const float*)d_in[12];
    const float* Wt    = (const float*)d_in[13];
    const float* Wg    = (const float*)d_in[14];

    float* ws  = (float*)d_ws;
    float* Qb  = ws;                      // 4194304 floats (B,T,C)
    float* Kb  = Qb + 4194304;
    float* Vb  = Kb + 4194304;
    float* Yb  = Vb + 4194304;
    float* Gb  = Yb + 4194304;            // 262144 (4,B,T,H)
    float* Mc  = Gb + 262144;             // 131072 (B,H,D,D)
    float* Sc  = Mc + 131072;             // 131072
    float* CSb = Sc + 131072;             // 8388608 (B,H,CS,D,D)
    float* Zb  = CSb + 8388608;           // 8388608
    unsigned short* su = (unsigned short*)CSb;
    unsigned short* xh  = su;
    unsigned short* xl  = su + 4194304;
    unsigned short* Wqh = su + 8388608,  *Wql = su + 9437184;
    unsigned short* Wkh = su + 10485760, *Wkl = su + 11534336;
    unsigned short* Wvh = su + 12582912, *Wvl = su + 13631488;
    float* bufA = Zb;

    hipMemsetAsync(Mc, 0, 2 * 131072 * sizeof(float), stream);

    split_kernel<<<4096, 256, 0, stream>>>(x, xh, xl, 4194304);
    split_kernel<<<1024, 256, 0, stream>>>(Wq, Wqh, Wql, 1048576);
    split_kernel<<<1024, 256, 0, stream>>>(Wk, Wkh, Wkl, 1048576);
    split_kernel<<<1024, 256, 0, stream>>>(Wv, Wvh, Wvl, 1048576);

    dim3 gs(C_ / 128, (B_ * T_) / 128);
    gemm_split<<<gs, 256, 0, stream>>>(xh, xl, Wqh, Wql, bufA);
    conv_kernel<<<B_ * T_, 256, 0, stream>>>(bufA, cqw, cqb, Qb, 1);
    gemm_split<<<gs, 256, 0, stream>>>(xh, xl, Wkh, Wkl, bufA);
    conv_kernel<<<B_ * T_, 256, 0, stream>>>(bufA, ckw, ckb, Kb, 2);
    gemm_split<<<gs, 256, 0, stream>>>(xh, xl, Wvh, Wvl, bufA);
    conv_kernel<<<B_ * T_, 256, 0, stream>>>(bufA, cvw, cvb, Vb, 0);
    gates_kernel<<<B_ * T_, 256, 0, stream>>>(x, Wa, We, Wt, Wg, Gb);

    chunk_s_kernel<<<B_ * H_ * 8, 256, 0, stream>>>(Kb, Vb, Gb, Mc, Sc, CSb, 0);
    for (int ch = 0; ch < NC_; ++ch) {
        polar_kernel<<<B_ * H_ * CS_, 256, 0, stream>>>(CSb, Zb);
        fused_my_cs<<<B_ * H_ * 8, 256, 0, stream>>>(Zb, Qb, Kb, Vb, Gb, Mc, Sc, CSb, Yb, ch);
    }

    unsigned short* Ybh = su, *Ybl = su + 4194304;
    unsigned short* Wph = su + 8388608, *Wpl = su + 9437184;
    split_kernel<<<4096, 256, 0, stream>>>(Yb, Ybh, Ybl, 4194304);
    split_kernel<<<1024, 256, 0, stream>>>(Wproj, Wph, Wpl, 1048576);
    gemm_split<<<gs, 256, 0, stream>>>(Ybh, Ybl, Wph, Wpl, (float*)d_out);
}

// Round 8
// 3578.458 us; speedup vs baseline: 4.0228x; 1.0148x over previous
//
#include <hip/hip_runtime.h>
#include <hip/hip_bf16.h>
#include <math.h>

#define B_ 2
#define T_ 2048
#define C_ 1024
#define H_ 16
#define D_ 64
#define CS_ 64
#define NC_ 32
#define NS_ 5
#define IST 136   // interleaved row stride in shorts (64 elems * 2 + 8 pad; 16B-aligned)

typedef __attribute__((ext_vector_type(8))) short bf16x8;
typedef __attribute__((ext_vector_type(4))) float f32x4;

__device__ inline void split2(float x, unsigned short& h, unsigned short& l) {
    __hip_bfloat16 bh = __float2bfloat16(x);           // hw cvt
    float lo = x - __bfloat162float(bh);
    __hip_bfloat16 bl = __float2bfloat16(lo);
    h = __builtin_bit_cast(unsigned short, bh);
    l = __builtin_bit_cast(unsigned short, bl);
}

// ---------------------------------------------------------------------------
// split f32 -> (hi, lo) bf16 buffers
// ---------------------------------------------------------------------------
__global__ __launch_bounds__(256) void split_kernel(const float* __restrict__ src,
                                                    unsigned short* __restrict__ hi,
                                                    unsigned short* __restrict__ lo,
                                                    int n) {
    int i = (blockIdx.x * 256 + threadIdx.x) * 4;
    if (i >= n) return;
    float4 v = *(const float4*)&src[i];
    unsigned short h0, l0, h1, l1, h2, l2, h3, l3;
    split2(v.x, h0, l0); split2(v.y, h1, l1);
    split2(v.z, h2, l2); split2(v.w, h3, l3);
    uint2 hv = make_uint2((unsigned)h0 | ((unsigned)h1 << 16), (unsigned)h2 | ((unsigned)h3 << 16));
    uint2 lv = make_uint2((unsigned)l0 | ((unsigned)l1 << 16), (unsigned)l2 | ((unsigned)l3 << 16));
    *(uint2*)&hi[i] = hv;
    *(uint2*)&lo[i] = lv;
}

// ---------------------------------------------------------------------------
// Split-precision bf16 MFMA GEMM (unchanged).
// ---------------------------------------------------------------------------
__global__ __launch_bounds__(256, 1) void gemm_split(const unsigned short* __restrict__ Ah,
                                                     const unsigned short* __restrict__ Al,
                                                     const unsigned short* __restrict__ Bh,
                                                     const unsigned short* __restrict__ Bl,
                                                     float* __restrict__ out) {
    __shared__ __align__(16) unsigned short sAh[128 * 72];
    __shared__ __align__(16) unsigned short sAl[128 * 72];
    __shared__ __align__(16) unsigned short sBh[128 * 72];
    __shared__ __align__(16) unsigned short sBl[128 * 72];
    int tid = threadIdx.x;
    int m0 = blockIdx.y * 128, n0 = blockIdx.x * 128;
    int w = tid >> 6, lane = tid & 63, q = lane >> 4, c = lane & 15;
    int mq = (w >> 1) * 64, nq = (w & 1) * 64;
    f32x4 acc[4][4];
    #pragma unroll
    for (int i = 0; i < 4; i++)
        #pragma unroll
        for (int j = 0; j < 4; j++) acc[i][j] = (f32x4){0.f, 0.f, 0.f, 0.f};
    int lrow = tid >> 2, lseg = (tid & 3) * 16;
    for (int kt = 0; kt < C_; kt += 64) {
        #pragma unroll
        for (int rr = 0; rr < 2; rr++) {
            int row = lrow + rr * 64;
            const size_t ga = (size_t)(m0 + row) * C_ + kt + lseg;
            const size_t gb = (size_t)(n0 + row) * C_ + kt + lseg;
            bf16x8 vah0 = *(const bf16x8*)&Ah[ga];
            bf16x8 vah1 = *(const bf16x8*)&Ah[ga + 8];
            bf16x8 val0 = *(const bf16x8*)&Al[ga];
            bf16x8 val1 = *(const bf16x8*)&Al[ga + 8];
            bf16x8 vbh0 = *(const bf16x8*)&Bh[gb];
            bf16x8 vbh1 = *(const bf16x8*)&Bh[gb + 8];
            bf16x8 vbl0 = *(const bf16x8*)&Bl[gb];
            bf16x8 vbl1 = *(const bf16x8*)&Bl[gb + 8];
            *(bf16x8*)&sAh[row * 72 + lseg] = vah0;
            *(bf16x8*)&sAh[row * 72 + lseg + 8] = vah1;
            *(bf16x8*)&sAl[row * 72 + lseg] = val0;
            *(bf16x8*)&sAl[row * 72 + lseg + 8] = val1;
            *(bf16x8*)&sBh[row * 72 + lseg] = vbh0;
            *(bf16x8*)&sBh[row * 72 + lseg + 8] = vbh1;
            *(bf16x8*)&sBl[row * 72 + lseg] = vbl0;
            *(bf16x8*)&sBl[row * 72 + lseg + 8] = vbl1;
        }
        __syncthreads();
        #pragma unroll
        for (int t = 0; t < 2; t++) {
            bf16x8 af[4][2], bfr[4][2];
            #pragma unroll
            for (int i = 0; i < 4; i++) {
                af[i][0] = *(const bf16x8*)&sAh[(mq + 16 * i + c) * 72 + t * 32 + q * 8];
                af[i][1] = *(const bf16x8*)&sAl[(mq + 16 * i + c) * 72 + t * 32 + q * 8];
            }
            #pragma unroll
            for (int j = 0; j < 4; j++) {
                bfr[j][0] = *(const bf16x8*)&sBh[(nq + 16 * j + c) * 72 + t * 32 + q * 8];
                bfr[j][1] = *(const bf16x8*)&sBl[(nq + 16 * j + c) * 72 + t * 32 + q * 8];
            }
            #pragma unroll
            for (int i = 0; i < 4; i++)
                #pragma unroll
                for (int j = 0; j < 4; j++) {
                    acc[i][j] = __builtin_amdgcn_mfma_f32_16x16x32_bf16(af[i][0], bfr[j][0], acc[i][j], 0, 0, 0);
                    acc[i][j] = __builtin_amdgcn_mfma_f32_16x16x32_bf16(af[i][0], bfr[j][1], acc[i][j], 0, 0, 0);
                    acc[i][j] = __builtin_amdgcn_mfma_f32_16x16x32_bf16(af[i][1], bfr[j][0], acc[i][j], 0, 0, 0);
                }
        }
        __syncthreads();
    }
    #pragma unroll
    for (int i = 0; i < 4; i++)
        #pragma unroll
        for (int j = 0; j < 4; j++)
            #pragma unroll
            for (int r = 0; r < 4; r++)
                out[(size_t)(m0 + mq + 16 * i + 4 * q + r) * C_ + n0 + nq + 16 * j + c] = acc[i][j][r];
}

// ---------------------------------------------------------------------------
// Causal depthwise conv (K=4) + optional per-head RMS norm + optional poly.
// ---------------------------------------------------------------------------
__global__ __launch_bounds__(256) void conv_kernel(const float* __restrict__ xin,
                                                   const float* __restrict__ w,
                                                   const float* __restrict__ bias,
                                                   float* __restrict__ out, int mode) {
    int bt = blockIdx.x;
    int t = bt & (T_ - 1);
    int tid = threadIdx.x;
    int c0 = tid * 4;
    float4 w4[4];
    #pragma unroll
    for (int i = 0; i < 4; i++) w4[i] = *(const float4*)&w[(c0 + i) * 4];
    float4 bi = *(const float4*)&bias[c0];
    float4 xs[4];
    #pragma unroll
    for (int j = 0; j < 4; j++) {
        int tt = t - 3 + j;
        xs[j] = (tt >= 0) ? *(const float4*)&xin[(bt - 3 + j) * C_ + c0]
                          : make_float4(0.f, 0.f, 0.f, 0.f);
    }
    float y0 = bi.x + w4[0].x * xs[0].x + w4[0].y * xs[1].x + w4[0].z * xs[2].x + w4[0].w * xs[3].x;
    float y1 = bi.y + w4[1].x * xs[0].y + w4[1].y * xs[1].y + w4[1].z * xs[2].y + w4[1].w * xs[3].y;
    float y2 = bi.z + w4[2].x * xs[0].z + w4[2].y * xs[1].z + w4[2].z * xs[2].z + w4[2].w * xs[3].z;
    float y3 = bi.w + w4[3].x * xs[0].w + w4[3].y * xs[1].w + w4[3].z * xs[2].w + w4[3].w * xs[3].w;
    if (mode >= 1) {
        float ss = y0 * y0 + y1 * y1 + y2 * y2 + y3 * y3;
        ss += __shfl_xor(ss, 1);
        ss += __shfl_xor(ss, 2);
        ss += __shfl_xor(ss, 4);
        ss += __shfl_xor(ss, 8);
        float sc = rsqrtf(ss * (1.f / 64.f) + 1e-6f);
        y0 *= sc; y1 *= sc; y2 *= sc; y3 *= sc;
        if (mode == 2) {
            y0 += 0.5f * y0 * y0; y1 += 0.5f * y1 * y1;
            y2 += 0.5f * y2 * y2; y3 += 0.5f * y3 * y3;
        }
    }
    *(float4*)&out[bt * C_ + c0] = make_float4(y0, y1, y2, y3);
}

// ---------------------------------------------------------------------------
// Gate projections.
// ---------------------------------------------------------------------------
__global__ __launch_bounds__(256) void gates_kernel(const float* __restrict__ x,
                                                    const float* __restrict__ Wa,
                                                    const float* __restrict__ We,
                                                    const float* __restrict__ Wt,
                                                    const float* __restrict__ Wg,
                                                    float* __restrict__ gates) {
    __shared__ float xs[C_];
    int bt = blockIdx.x, tid = threadIdx.x;
    *(float4*)&xs[tid * 4] = *(const float4*)&x[bt * C_ + tid * 4];
    __syncthreads();
    int dot = tid >> 2, l = tid & 3;
    int g = dot >> 4, h = dot & 15;
    const float* Wp = (g == 0) ? Wa : (g == 1) ? We : (g == 2) ? Wt : Wg;
    const float* Wr = Wp + h * C_;
    float p = 0.f;
    for (int c = l * 4; c < C_; c += 16) {
        float4 wv = *(const float4*)&Wr[c];
        float4 xv = *(const float4*)&xs[c];
        p += wv.x * xv.x + wv.y * xv.y + wv.z * xv.z + wv.w * xv.w;
    }
    p += __shfl_xor(p, 1);
    p += __shfl_xor(p, 2);
    if (l == 0) gates[g * (B_ * T_ * H_) + bt * H_ + h] = 1.f / (1.f + __expf(-p));
}

// ---------------------------------------------------------------------------
// chunk_s: standalone (chunk 0 only) — unchanged.
// ---------------------------------------------------------------------------
__global__ __launch_bounds__(256) void chunk_s_kernel(const float* __restrict__ kbuf,
                                                      const float* __restrict__ vbuf,
                                                      const float* __restrict__ gates,
                                                      const float* __restrict__ Mc,
                                                      float* __restrict__ Sc,
                                                      float* __restrict__ chunkS,
                                                      int chunk) {
    __shared__ float Kc[CS_][68];
    __shared__ float Mrow[8][68];
    __shared__ float errS[CS_][8];
    __shared__ float thS[CS_], etS[CS_], gmS[CS_];
    int tid = threadIdx.x;
    int idx = blockIdx.x;
    int vt = idx & 7, h = (idx >> 3) & 15, b = idx >> 7;
    int c0t = chunk * CS_;
    {
        int row = tid >> 2, col = (tid & 3) * 16;
        const float* src = &kbuf[((size_t)(b * T_ + c0t + row) * H_ + h) * D_];
        #pragma unroll
        for (int i = 0; i < 4; i++)
            *(float4*)&Kc[row][col + i * 4] = *(const float4*)&src[col + i * 4];
    }
    if (tid < 128) {
        int v = tid >> 4, cc = (tid & 15) * 4;
        *(float4*)&Mrow[v][cc] =
            *(const float4*)&Mc[((size_t)(b * H_ + h)) * 4096 + (vt * 8 + v) * 64 + cc];
    }
    if (tid < CS_)           thS[tid] = gates[2 * (B_ * T_ * H_) + (b * T_ + c0t + tid) * H_ + h];
    else if (tid < 2 * CS_)  { int t = tid - CS_;     etS[t] = gates[1 * (B_ * T_ * H_) + (b * T_ + c0t + t) * H_ + h]; }
    else if (tid < 3 * CS_)  { int t = tid - 2 * CS_; gmS[t] = gates[3 * (B_ * T_ * H_) + (b * T_ + c0t + t) * H_ + h]; }
    __syncthreads();
    {
        int t = tid >> 2, v0 = (tid & 3) * 2;
        float s0 = 0.f, s1 = 0.f;
        #pragma unroll
        for (int k = 0; k < 64; k += 4) {
            float4 kv = *(float4*)&Kc[t][k];
            float4 m0 = *(float4*)&Mrow[v0][k];
            float4 m1 = *(float4*)&Mrow[v0 + 1][k];
            s0 += kv.x * m0.x + kv.y * m0.y + kv.z * m0.z + kv.w * m0.w;
            s1 += kv.x * m1.x + kv.y * m1.y + kv.z * m1.z + kv.w * m1.w;
        }
        const float* vp = &vbuf[((size_t)(b * T_ + c0t + t) * H_ + h) * D_ + vt * 8 + v0];
        errS[t][v0]     = s0 - vp[0];
        errS[t][v0 + 1] = s1 - vp[1];
    }
    __syncthreads();
    int vl = tid >> 5;
    int kk = (tid & 31) * 2;
    size_t sIdx = ((size_t)(b * H_ + h)) * 4096 + (vt * 8 + vl) * 64 + kk;
    float S0 = Sc[sIdx], S1 = Sc[sIdx + 1];
    float ring0[16] = {}, ring1[16] = {};
    float cum0 = 0.f, cum1 = 0.f;
    for (int cb = 0; cb < 4; ++cb) {
        #pragma unroll
        for (int ci = 0; ci < 16; ++ci) {
            int c = cb * 16 + ci;
            float er = 2.f * errS[c][vl];
            float2 kv = *(float2*)&Kc[c][kk];
            float g = gmS[c];
            cum0 += g * er * kv.x;
            cum1 += g * er * kv.y;
            float uw0 = cum0 - ring0[ci];
            float uw1 = cum1 - ring1[ci];
            ring0[ci] = cum0; ring1[ci] = cum1;
            float th = thS[c], et = etS[c];
            S0 = th * S0 - et * uw0;
            S1 = th * S1 - et * uw1;
            size_t o = ((size_t)((b * H_ + h) * CS_ + c)) * 4096 + (vt * 8 + vl) * 64 + kk;
            *(float2*)&chunkS[o] = make_float2(S0, S1);
        }
    }
    Sc[sIdx] = S0; Sc[sIdx + 1] = S1;
}

// ---------------------------------------------------------------------------
// Polar-Express, interleaved-split bf16 MFMA, QUADRANT ownership:
// wave w owns 32x32 output quadrant (R=w>>1, C=w&1) of every matmul.
// A-frags = 2 row-tiles (rows 32R..), B-frags = 2 col-tiles (rows 32C.. of the
// B-source buffer). Diagonal waves (R==C) reuse A-frags as B-frags in P1/P2.
// Structure: Y = X Xt ; Z2 = Y Y ; W = bY + cZ2 (regs) ; X' = aX + W X.
// Barriers/iter: b1 (Y done), b2 (Y reads done), b3 (W done), b4 (Xti reads
// done) — last iter skips the X writeback and b4.
// ---------------------------------------------------------------------------
__device__ inline bf16x8 swap16(bf16x8 v) {
    union { bf16x8 v8; unsigned int u[4]; } x;
    x.v8 = v;
    #pragma unroll
    for (int i = 0; i < 4; i++) x.u[i] = (x.u[i] >> 16) | (x.u[i] << 16);
    return x.v8;
}
__device__ inline bf16x8 ldI(const unsigned short* buf, int row, int g, int q) {
    return *(const bf16x8*)&buf[row * IST + g * 32 + q * 8];
}
// out[rt][ctl] = A(rows ar0..ar0+31 of bufA) x B^T(rows br0..br0+31 of bufB)
__device__ inline void mmQ(f32x4 (&out)[2][2],
                           const unsigned short* bufA, const unsigned short* bufB,
                           int ar0, int br0, int c, int q, bool share) {
    bf16x8 a[2][4], as[2][4];
    #pragma unroll
    for (int rt = 0; rt < 2; rt++)
        #pragma unroll
        for (int g = 0; g < 4; g++) {
            a[rt][g] = ldI(bufA, ar0 + 16 * rt + c, g, q);
            as[rt][g] = swap16(a[rt][g]);
        }
    #pragma unroll
    for (int ctl = 0; ctl < 2; ctl++) {
        bf16x8 b[4];
        if (share && ar0 == br0) {
            #pragma unroll
            for (int g = 0; g < 4; g++) b[g] = a[ctl][g];
        } else {
            #pragma unroll
            for (int g = 0; g < 4; g++) b[g] = ldI(bufB, br0 + 16 * ctl + c, g, q);
        }
        #pragma unroll
        for (int rt = 0; rt < 2; rt++) {
            f32x4 acc = {0.f, 0.f, 0.f, 0.f};
            #pragma unroll
            for (int g = 0; g < 4; g++) {
                acc = __builtin_amdgcn_mfma_f32_16x16x32_bf16(a[rt][g], b[g], acc, 0, 0, 0);
                acc = __builtin_amdgcn_mfma_f32_16x16x32_bf16(as[rt][g], b[g], acc, 0, 0, 0);
            }
            out[rt][ctl] = acc;
        }
    }
}
__device__ inline void writeRowQ(unsigned short* buf, const f32x4 (&M)[2][2],
                                 int ar0, int br0, int q, int c) {
    #pragma unroll
    for (int rt = 0; rt < 2; rt++)
        #pragma unroll
        for (int ctl = 0; ctl < 2; ctl++)
            #pragma unroll
            for (int r = 0; r < 4; r++) {
                unsigned short h, l;
                split2(M[rt][ctl][r], h, l);
                *(unsigned int*)&buf[(ar0 + 16 * rt + 4 * q + r) * IST + 2 * (br0 + 16 * ctl + c)] =
                    (unsigned)h | ((unsigned)l << 16);
            }
}
__device__ inline void writeColQ(unsigned short* buf, const f32x4 (&M)[2][2],
                                 int ar0, int br0, int q, int c) {
    #pragma unroll
    for (int rt = 0; rt < 2; rt++)
        #pragma unroll
        for (int ctl = 0; ctl < 2; ctl++) {
            unsigned int d[4];
            #pragma unroll
            for (int r = 0; r < 4; r++) {
                unsigned short h, l;
                split2(M[rt][ctl][r], h, l);
                d[r] = (unsigned)h | ((unsigned)l << 16);
            }
            *(uint4*)&buf[(br0 + 16 * ctl + c) * IST + 2 * (ar0 + 16 * rt + 4 * q)] =
                make_uint4(d[0], d[1], d[2], d[3]);
        }
}

__global__ __launch_bounds__(256, 3) void polar_kernel(const float* __restrict__ chunkS,
                                                       float* __restrict__ Z) {
    __shared__ __align__(16) unsigned short Xi[64 * IST];
    __shared__ __align__(16) unsigned short Xti[64 * IST];
    __shared__ __align__(16) unsigned short Yi[64 * IST];
    __shared__ float red[4];
    int tid = threadIdx.x;
    int w = tid >> 6, lane = tid & 63;
    int q = lane >> 4, c = lane & 15;
    int ar0 = (w >> 1) * 32, br0 = (w & 1) * 32;
    size_t base = (size_t)blockIdx.x * 4096;

    f32x4 Xc[2][2];
    float ss = 0.f;
    #pragma unroll
    for (int rt = 0; rt < 2; rt++)
        #pragma unroll
        for (int ctl = 0; ctl < 2; ctl++)
            #pragma unroll
            for (int r = 0; r < 4; r++) {
                float v = chunkS[base + (size_t)(ar0 + 16 * rt + 4 * q + r) * 64 + br0 + 16 * ctl + c];
                Xc[rt][ctl][r] = v;
                ss += v * v;
            }
    ss += __shfl_xor(ss, 1);  ss += __shfl_xor(ss, 2);  ss += __shfl_xor(ss, 4);
    ss += __shfl_xor(ss, 8);  ss += __shfl_xor(ss, 16); ss += __shfl_xor(ss, 32);
    if (lane == 0) red[w] = ss;
    __syncthreads();
    float sc = 1.f / (sqrtf(red[0] + red[1] + red[2] + red[3]) + 1e-7f);
    #pragma unroll
    for (int rt = 0; rt < 2; rt++)
        #pragma unroll
        for (int ctl = 0; ctl < 2; ctl++)
            #pragma unroll
            for (int r = 0; r < 4; r++) Xc[rt][ctl][r] *= sc;
    writeRowQ(Xi, Xc, ar0, br0, q, c);
    writeColQ(Xti, Xc, ar0, br0, q, c);
    __syncthreads();

    const float na = 3.4445f, nb = -4.7750f, ncf = 2.0315f;
    f32x4 Yc[2][2], Tc[2][2];
    for (int it = 0; it < NS_; ++it) {
        // ---- P1: Y = X Xt (A,B both from Xi; diag waves share frags) ----
        mmQ(Yc, Xi, Xi, ar0, br0, c, q, true);
        writeRowQ(Yi, Yc, ar0, br0, q, c);
        __syncthreads();   // b1: Yi complete; Xi reads done
        // ---- P2: Z2 = Y Y ; W = b*Y + c*Z2 in regs ----
        mmQ(Tc, Yi, Yi, ar0, br0, c, q, true);
        #pragma unroll
        for (int rt = 0; rt < 2; rt++)
            #pragma unroll
            for (int ctl = 0; ctl < 2; ctl++)
                #pragma unroll
                for (int r = 0; r < 4; r++)
                    Yc[rt][ctl][r] = nb * Yc[rt][ctl][r] + ncf * Tc[rt][ctl][r];
        __syncthreads();   // b2: Yi reads done -> safe to overwrite with W
        writeRowQ(Yi, Yc, ar0, br0, q, c);
        __syncthreads();   // b3: W complete (cross-wave A reads in P3)
        // ---- P3: V = W X (A from Yi, B from Xti) ; X' = aX + V ----
        mmQ(Tc, Yi, Xti, ar0, br0, c, q, false);
        #pragma unroll
        for (int rt = 0; rt < 2; rt++)
            #pragma unroll
            for (int ctl = 0; ctl < 2; ctl++)
                #pragma unroll
                for (int r = 0; r < 4; r++)
                    Xc[rt][ctl][r] = na * Xc[rt][ctl][r] + Tc[rt][ctl][r];
        if (it != NS_ - 1) {
            writeRowQ(Xi, Xc, ar0, br0, q, c);   // Xi unread since b1
            __syncthreads();                      // b4: Xti reads done; Xi visible
            writeColQ(Xti, Xc, ar0, br0, q, c);   // first read next-iter P3 (after b3')
        }
    }
    #pragma unroll
    for (int rt = 0; rt < 2; rt++)
        #pragma unroll
        for (int ctl = 0; ctl < 2; ctl++)
            #pragma unroll
            for (int r = 0; r < 4; r++)
                Z[base + (size_t)(ar0 + 16 * rt + 4 * q + r) * 64 + br0 + 16 * ctl + c] = Xc[rt][ctl][r];
}

// ---------------------------------------------------------------------------
// Fused: m_y(ch) + chunk_s(ch+1); Zb prefetched one step ahead (branchless
// wrapped index) and unrolled x4 so independent shuffle-reductions pipeline.
// ---------------------------------------------------------------------------
__global__ __launch_bounds__(256) void fused_my_cs(const float* __restrict__ Zb,
                                                   const float* __restrict__ qbuf,
                                                   const float* __restrict__ kbuf,
                                                   const float* __restrict__ vbuf,
                                                   const float* __restrict__ gates,
                                                   float* __restrict__ Mc,
                                                   float* __restrict__ Sc,
                                                   float* __restrict__ chunkS,
                                                   float* __restrict__ ybuf,
                                                   int chunk) {
    __shared__ float buf[CS_][68];
    __shared__ float Mrow[8][68];
    __shared__ float errS[CS_][8];
    __shared__ float alS[CS_], thS[CS_], etS[CS_], gmS[CS_];
    int tid = threadIdx.x, idx = blockIdx.x;
    int vt = idx & 7, h = (idx >> 3) & 15, b = idx >> 7;
    int c0t = chunk * CS_;
    {
        int row = tid >> 2, col = (tid & 3) * 16;
        const float* src = &qbuf[((size_t)(b * T_ + c0t + row) * H_ + h) * D_];
        #pragma unroll
        for (int i = 0; i < 4; i++)
            *(float4*)&buf[row][col + i * 4] = *(const float4*)&src[col + i * 4];
    }
    if (tid < CS_) alS[tid] = gates[0 * (B_ * T_ * H_) + (b * T_ + c0t + tid) * H_ + h];
    __syncthreads();
    int vl = tid >> 5, k0 = (tid & 31) * 2;
    size_t mIdx = ((size_t)(b * H_ + h)) * 4096 + (vt * 8 + vl) * 64 + k0;
    size_t zrow = ((size_t)(b * H_ + h) * CS_) * 4096 + (vt * 8 + vl) * 64 + k0;
    float M0 = Mc[mIdx], M1 = Mc[mIdx + 1];
    float2 z = *(const float2*)&Zb[zrow];
    #pragma unroll 4
    for (int c = 0; c < CS_; c++) {
        int cn = (c + 1) & (CS_ - 1);
        float2 znext = *(const float2*)&Zb[zrow + (size_t)cn * 4096];
        float al = alS[c];
        M0 = al * M0 + z.x;
        M1 = al * M1 + z.y;
        float2 qv = *(float2*)&buf[c][k0];
        float p = M0 * qv.x + M1 * qv.y;
        p += __shfl_xor(p, 1);  p += __shfl_xor(p, 2);  p += __shfl_xor(p, 4);
        p += __shfl_xor(p, 8);  p += __shfl_xor(p, 16);
        if ((tid & 31) == 0)
            ybuf[((size_t)(b * T_ + c0t + c) * H_ + h) * D_ + vt * 8 + vl] = p;
        z = znext;
    }
    Mc[mIdx] = M0; Mc[mIdx + 1] = M1;
    if (chunk + 1 >= NC_) return;
    int c1t = c0t + CS_;
    __syncthreads();
    Mrow[vl][k0] = M0; Mrow[vl][k0 + 1] = M1;
    {
        int row = tid >> 2, col = (tid & 3) * 16;
        const float* src = &kbuf[((size_t)(b * T_ + c1t + row) * H_ + h) * D_];
        #pragma unroll
        for (int i = 0; i < 4; i++)
            *(float4*)&buf[row][col + i * 4] = *(const float4*)&src[col + i * 4];
    }
    if (tid < CS_)           thS[tid] = gates[2 * (B_ * T_ * H_) + (b * T_ + c1t + tid) * H_ + h];
    else if (tid < 2 * CS_)  { int t = tid - CS_;     etS[t] = gates[1 * (B_ * T_ * H_) + (b * T_ + c1t + t) * H_ + h]; }
    else if (tid < 3 * CS_)  { int t = tid - 2 * CS_; gmS[t] = gates[3 * (B_ * T_ * H_) + (b * T_ + c1t + t) * H_ + h]; }
    __syncthreads();
    {
        int t = tid >> 2, v0 = (tid & 3) * 2;
        float s0 = 0.f, s1 = 0.f;
        #pragma unroll
        for (int k = 0; k < 64; k += 4) {
            float4 kv = *(float4*)&buf[t][k];
            float4 m0v = *(float4*)&Mrow[v0][k];
            float4 m1v = *(float4*)&Mrow[v0 + 1][k];
            s0 += kv.x * m0v.x + kv.y * m0v.y + kv.z * m0v.z + kv.w * m0v.w;
            s1 += kv.x * m1v.x + kv.y * m1v.y + kv.z * m1v.z + kv.w * m1v.w;
        }
        const float* vp = &vbuf[((size_t)(b * T_ + c1t + t) * H_ + h) * D_ + vt * 8 + v0];
        errS[t][v0]     = s0 - vp[0];
        errS[t][v0 + 1] = s1 - vp[1];
    }
    __syncthreads();
    float S0 = Sc[mIdx], S1 = Sc[mIdx + 1];
    float ring0[16] = {}, ring1[16] = {};
    float cum0 = 0.f, cum1 = 0.f;
    for (int cb = 0; cb < 4; ++cb) {
        #pragma unroll
        for (int ci = 0; ci < 16; ++ci) {
            int cc = cb * 16 + ci;
            float er = 2.f * errS[cc][vl];
            float2 kv = *(float2*)&buf[cc][k0];
            float g = gmS[cc];
            cum0 += g * er * kv.x;
            cum1 += g * er * kv.y;
            float uw0 = cum0 - ring0[ci];
            float uw1 = cum1 - ring1[ci];
            ring0[ci] = cum0; ring1[ci] = cum1;
            float th = thS[cc], et = etS[cc];
            S0 = th * S0 - et * uw0;
            S1 = th * S1 - et * uw1;
            size_t o = ((size_t)((b * H_ + h) * CS_ + cc)) * 4096 + (vt * 8 + vl) * 64 + k0;
            *(float2*)&chunkS[o] = make_float2(S0, S1);
        }
    }
    Sc[mIdx] = S0; Sc[mIdx + 1] = S1;
}

// ---------------------------------------------------------------------------
extern "C" void kernel_launch(void* const* d_in, const int* in_sizes, int n_in,
                              void* d_out, int out_size, void* d_ws, size_t ws_size,
                              hipStream_t stream) {
    (void)in_sizes; (void)n_in; (void)out_size; (void)ws_size;
    const float* x     = (const float*)d_in[0];
    const float* Wq    = (const float*)d_in[1];
    const float* Wk    = (const float*)d_in[2];
    const float* Wv    = (const float*)d_in[3];
    const float* Wproj = (const float*)d_in[4];
    const float* cqw   = (const float*)d_in[5];
    const float* cqb   = (const float*)d_in[6];
    const float* ckw   = (const float*)d_in[7];
    const float* ckb   = (const float*)d_in[8];
    const float* cvw   = (const float*)d_in[9];
    const float* cvb   = (const float*)d_in[10];
    const float* Wa    = (const float*)d_in[11];
    const float* We    = (const float*)d_in[12];
    const float* Wt    = (const float*)d_in[13];
    const float* Wg    = (const float*)d_in[14];

    float* ws  = (float*)d_ws;
    float* Qb  = ws;                      // 4194304 floats (B,T,C)
    float* Kb  = Qb + 4194304;
    float* Vb  = Kb + 4194304;
    float* Yb  = Vb + 4194304;
    float* Gb  = Yb + 4194304;            // 262144 (4,B,T,H)
    float* Mc  = Gb + 262144;             // 131072 (B,H,D,D)
    float* Sc  = Mc + 131072;             // 131072
    float* CSb = Sc + 131072;             // 8388608 (B,H,CS,D,D)
    float* Zb  = CSb + 8388608;           // 8388608
    unsigned short* su = (unsigned short*)CSb;
    unsigned short* xh  = su;
    unsigned short* xl  = su + 4194304;
    unsigned short* Wqh = su + 8388608,  *Wql = su + 9437184;
    unsigned short* Wkh = su + 10485760, *Wkl = su + 11534336;
    unsigned short* Wvh = su + 12582912, *Wvl = su + 13631488;
    float* bufA = Zb;

    hipMemsetAsync(Mc, 0, 2 * 131072 * sizeof(float), stream);

    split_kernel<<<4096, 256, 0, stream>>>(x, xh, xl, 4194304);
    split_kernel<<<1024, 256, 0, stream>>>(Wq, Wqh, Wql, 1048576);
    split_kernel<<<1024, 256, 0, stream>>>(Wk, Wkh, Wkl, 1048576);
    split_kernel<<<1024, 256, 0, stream>>>(Wv, Wvh, Wvl, 1048576);

    dim3 gs(C_ / 128, (B_ * T_) / 128);
    gemm_split<<<gs, 256, 0, stream>>>(xh, xl, Wqh, Wql, bufA);
    conv_kernel<<<B_ * T_, 256, 0, stream>>>(bufA, cqw, cqb, Qb, 1);
    gemm_split<<<gs, 256, 0, stream>>>(xh, xl, Wkh, Wkl, bufA);
    conv_kernel<<<B_ * T_, 256, 0, stream>>>(bufA, ckw, ckb, Kb, 2);
    gemm_split<<<gs, 256, 0, stream>>>(xh, xl, Wvh, Wvl, bufA);
    conv_kernel<<<B_ * T_, 256, 0, stream>>>(bufA, cvw, cvb, Vb, 0);
    gates_kernel<<<B_ * T_, 256, 0, stream>>>(x, Wa, We, Wt, Wg, Gb);

    chunk_s_kernel<<<B_ * H_ * 8, 256, 0, stream>>>(Kb, Vb, Gb, Mc, Sc, CSb, 0);
    for (int ch = 0; ch < NC_; ++ch) {
        polar_kernel<<<B_ * H_ * CS_, 256, 0, stream>>>(CSb, Zb);
        fused_my_cs<<<B_ * H_ * 8, 256, 0, stream>>>(Zb, Qb, Kb, Vb, Gb, Mc, Sc, CSb, Yb, ch);
    }

    unsigned short* Ybh = su, *Ybl = su + 4194304;
    unsigned short* Wph = su + 8388608, *Wpl = su + 9437184;
    split_kernel<<<4096, 256, 0, stream>>>(Yb, Ybh, Ybl, 4194304);
    split_kernel<<<1024, 256, 0, stream>>>(Wproj, Wph, Wpl, 1048576);
    gemm_split<<<gs, 256, 0, stream>>>(Ybh, Ybl, Wph, Wpl, (float*)d_out);
}